// Round 5
// baseline (272.435 us; speedup 1.0000x reference)
//
#include <hip/hip_runtime.h>
#include <hip/hip_bf16.h>

// LinearAttention on MI355X (gfx950). Inputs/outputs fp32; internal bf16 MFMA.
// B=4 N=4096 C=1024 H=16 D=64.
//  K0 cvt:            xb/wqkvb/wprojb = bf16(x / w_qkv / w_proj)
//  K1 gemm256<16384>: QKV^T[c, m] = sum_k w_qkv[c,k] * x[m,k], relu on c<2048 rows.
//  K2 ctx_kernel:     per (b,h,s): partial ctx[d,e] = sum_n V[d,n]K[e,n], partial ksum.
//  K3 out_kernel:     O[m, h*64+d] = z[n] * sum_e ctx[d,e] Q[e,n]   (bf16)
//  K4 gemm256<1024>:  out[m,co] = sum_c O[m,c] w_proj[co,c] + b_proj[co]  (fp32 out)
//
// gemm256 = 8-phase T3+T4 schedule (m201 template): 256x256 tile, BK=64,
// 8 waves (2Mx4N), K-tile split in 2 k-halves; phase = (k-half, fn-pair),
// 16 MFMA/phase; one half-tile staged per phase into the OPPOSITE dbuf
// (tile t+1 staged during group t -> no LDS write/read race by construction);
// counted vmcnt(4) at phases 1,3 only (drain-0 only on the last tile);
// setprio around MFMA (T5); pair-row XOR LDS swizzle (T2, both-sides via
// pre-swizzled global source + swizzled ds_read addr); bijective XCD block
// swizzle (T1).

typedef __bf16 bf16;
typedef __bf16 bf16x8 __attribute__((ext_vector_type(8)));
typedef __bf16 bf16x4 __attribute__((ext_vector_type(4)));
typedef float  f32x4  __attribute__((ext_vector_type(4)));

#define MFMA16(a, b, c) __builtin_amdgcn_mfma_f32_16x16x32_bf16((a), (b), (c), 0, 0, 0)

__device__ __forceinline__ void gload_lds16(const bf16* g, bf16* l) {
  // 16B per lane; LDS dest = wave-uniform base + lane*16 (linear layout required).
  __builtin_amdgcn_global_load_lds(
      (const __attribute__((address_space(1))) void*)g,
      (__attribute__((address_space(3))) void*)l, 16, 0, 0);
}

// ---------------------------------------------------------------------------
// K0: fp32 -> bf16 elementwise convert (float4 in, bf16x4 out), grid-stride.
// ---------------------------------------------------------------------------
__global__ __launch_bounds__(256) void cvt_f32_bf16(const float* __restrict__ src,
                                                    bf16* __restrict__ dst, long n) {
  const long stride4 = (long)gridDim.x * blockDim.x * 4;
  for (long j = ((long)blockIdx.x * blockDim.x + threadIdx.x) * 4; j < n; j += stride4) {
    const float4 v = *(const float4*)(src + j);
    bf16x4 o;
    o[0] = (bf16)v.x; o[1] = (bf16)v.y; o[2] = (bf16)v.z; o[3] = (bf16)v.w;
    *(bf16x4*)(dst + j) = o;
  }
}

// ---------------------------------------------------------------------------
// Half-tile LDS layout (per [dbuf][khalf]): 256 rows x 32 elems (16 KiB).
// Pair-row swizzle: elem (row, 8-chunk c) at offset
//   (row>>1)*64 + (phys3)*8,  phys3 = ((row&1)*4 + c) ^ ((row>>1)&7)
// -> ds_read_b128 with rows base+r15, chunk g is conflict-free.
// Staged by gload_lds with linear LDS dest + per-lane pre-swizzled global src.
// ---------------------------------------------------------------------------
__device__ __forceinline__ bf16x8 ldfrag(const bf16* half_, int row, int g) {
  const int off = ((row >> 1) << 6) + (((((row & 1) << 2) | g) ^ ((row >> 1) & 7)) << 3);
  return *(const bf16x8*)(half_ + off);
}

// ---------------------------------------------------------------------------
// gemm256: C[i,j] = sum_k A[i,k]*B[j,k], K=1024. A:[M,1024] B:[N,1024] bf16.
// Grid: dim3(N/256, M/256), 512 threads. Requires M%256==0, N%256==0,
// (gx*gy)%8==0, reluRows%256==0.
// ---------------------------------------------------------------------------
template <int LDC, typename CO>
__global__ __launch_bounds__(512, 2) void gemm256(const bf16* __restrict__ A,
                                                  const bf16* __restrict__ Bm,
                                                  CO* __restrict__ Co,
                                                  const float* __restrict__ bias,
                                                  const int reluRows) {
  __shared__ bf16 As[2][2][8192];   // [dbuf][khalf][256r x 32k swizzled]
  __shared__ bf16 Bs[2][2][8192];
  const int tid  = threadIdx.x;
  const int lane = tid & 63;
  const int w    = tid >> 6;      // wave 0..7
  const int wm   = w >> 2;        // 2 M-halves
  const int wn   = w & 3;         // 4 N-quarters

  // T1: bijective XCD swizzle; smaller grid dim innermost (operand-panel reuse)
  const int gx = gridDim.x, gy = gridDim.y;
  const int nwg = gx * gy;
  const int id  = blockIdx.x + gx * blockIdx.y;
  const int sid = (id & 7) * (nwg >> 3) + (id >> 3);
  int bx, by;
  if (gx < gy) { bx = sid % gx; by = sid / gx; }
  else         { by = sid % gy; bx = sid / gy; }
  const int i0 = by * 256;
  const int j0 = bx * 256;

  // Staging geometry (per lane): q3 = logical (row-parity, chunk) packed.
  const int q3   = (lane & 7) ^ (lane >> 3);
  const int row0 = 2 * (w * 8 + (lane >> 3)) + (q3 >> 2);  // pass adds 128
  const int c0   = q3 & 3;
  const bf16* Asrc = A  + (long)(i0 + row0) * 1024 + c0 * 8;  // + pass*131072 + kt*64 + kh*32
  const bf16* Bsrc = Bm + (long)(j0 + row0) * 1024 + c0 * 8;
  bf16* AldsW[2][2] = { { &As[0][0][w * 512], &As[0][1][w * 512] },
                        { &As[1][0][w * 512], &As[1][1][w * 512] } };
  bf16* BldsW[2][2] = { { &Bs[0][0][w * 512], &Bs[0][1][w * 512] },
                        { &Bs[1][0][w * 512], &Bs[1][1][w * 512] } };

  const int r15 = lane & 15, g = lane >> 4;
  const int arow = wm * 128 + r15;   // + fm*16
  const int brow = wn * 64 + r15;    // + fn*16

  f32x4 acc[8][4] = {};

#define STAGE_HALF(srcb, ldsw, kt, kh)                                   \
  do {                                                                   \
    const bf16* s_ = (srcb) + (kt) * 64 + (kh) * 32;                     \
    gload_lds16(s_,           (ldsw));                                   \
    gload_lds16(s_ + 131072,  (ldsw) + 4096);                            \
  } while (0)

  // Prologue: stage all 4 halves of tile 0 into dbuf 0; wait first 2 halves.
  STAGE_HALF(Asrc, AldsW[0][0], 0, 0);
  STAGE_HALF(Bsrc, BldsW[0][0], 0, 0);
  STAGE_HALF(Asrc, AldsW[0][1], 0, 1);
  STAGE_HALF(Bsrc, BldsW[0][1], 0, 1);
  asm volatile("s_waitcnt vmcnt(4)" ::: "memory");
  __builtin_amdgcn_s_barrier();

  for (int t = 0; t < 16; ++t) {
    const int d = t & 1, e = d ^ 1;
    bf16x8 af[8], bf0, bf1;

    // ---- phase 0: kh=0, fn {0,1}; stage tile t+1 A-kh0 ----
#pragma unroll
    for (int fm = 0; fm < 8; ++fm) af[fm] = ldfrag(&As[d][0][0], arow + fm * 16, g);
    bf0 = ldfrag(&Bs[d][0][0], brow + 0 * 16, g);
    bf1 = ldfrag(&Bs[d][0][0], brow + 1 * 16, g);
    if (t < 15) STAGE_HALF(Asrc, AldsW[e][0], t + 1, 0);
    __builtin_amdgcn_s_barrier();
    asm volatile("s_waitcnt lgkmcnt(0)" ::: "memory");
    __builtin_amdgcn_sched_barrier(0);
    __builtin_amdgcn_s_setprio(1);
#pragma unroll
    for (int fm = 0; fm < 8; ++fm) {
      acc[fm][0] = MFMA16(af[fm], bf0, acc[fm][0]);
      acc[fm][1] = MFMA16(af[fm], bf1, acc[fm][1]);
    }
    __builtin_amdgcn_s_setprio(0);
    __builtin_amdgcn_s_barrier();

    // ---- phase 1: kh=0, fn {2,3}; stage tile t+1 B-kh0; counted vmcnt ----
    bf0 = ldfrag(&Bs[d][0][0], brow + 2 * 16, g);
    bf1 = ldfrag(&Bs[d][0][0], brow + 3 * 16, g);
    if (t < 15) STAGE_HALF(Bsrc, BldsW[e][0], t + 1, 0);
    __builtin_amdgcn_s_barrier();
    asm volatile("s_waitcnt lgkmcnt(0)" ::: "memory");
    __builtin_amdgcn_sched_barrier(0);
    __builtin_amdgcn_s_setprio(1);
#pragma unroll
    for (int fm = 0; fm < 8; ++fm) {
      acc[fm][2] = MFMA16(af[fm], bf0, acc[fm][2]);
      acc[fm][3] = MFMA16(af[fm], bf1, acc[fm][3]);
    }
    __builtin_amdgcn_s_setprio(0);
    if (t < 15) { asm volatile("s_waitcnt vmcnt(4)" ::: "memory"); }
    else        { asm volatile("s_waitcnt vmcnt(0)" ::: "memory"); }
    __builtin_amdgcn_s_barrier();

    // ---- phase 2: kh=1, fn {0,1}; stage tile t+1 A-kh1 ----
#pragma unroll
    for (int fm = 0; fm < 8; ++fm) af[fm] = ldfrag(&As[d][1][0], arow + fm * 16, g);
    bf0 = ldfrag(&Bs[d][1][0], brow + 0 * 16, g);
    bf1 = ldfrag(&Bs[d][1][0], brow + 1 * 16, g);
    if (t < 15) STAGE_HALF(Asrc, AldsW[e][1], t + 1, 1);
    __builtin_amdgcn_s_barrier();
    asm volatile("s_waitcnt lgkmcnt(0)" ::: "memory");
    __builtin_amdgcn_sched_barrier(0);
    __builtin_amdgcn_s_setprio(1);
#pragma unroll
    for (int fm = 0; fm < 8; ++fm) {
      acc[fm][0] = MFMA16(af[fm], bf0, acc[fm][0]);
      acc[fm][1] = MFMA16(af[fm], bf1, acc[fm][1]);
    }
    __builtin_amdgcn_s_setprio(0);
    __builtin_amdgcn_s_barrier();

    // ---- phase 3: kh=1, fn {2,3}; stage tile t+1 B-kh1; counted vmcnt ----
    bf0 = ldfrag(&Bs[d][1][0], brow + 2 * 16, g);
    bf1 = ldfrag(&Bs[d][1][0], brow + 3 * 16, g);
    if (t < 15) STAGE_HALF(Bsrc, BldsW[e][1], t + 1, 1);
    __builtin_amdgcn_s_barrier();
    asm volatile("s_waitcnt lgkmcnt(0)" ::: "memory");
    __builtin_amdgcn_sched_barrier(0);
    __builtin_amdgcn_s_setprio(1);
#pragma unroll
    for (int fm = 0; fm < 8; ++fm) {
      acc[fm][2] = MFMA16(af[fm], bf0, acc[fm][2]);
      acc[fm][3] = MFMA16(af[fm], bf1, acc[fm][3]);
    }
    __builtin_amdgcn_s_setprio(0);
    if (t < 15) { asm volatile("s_waitcnt vmcnt(4)" ::: "memory"); }
    __builtin_amdgcn_s_barrier();
  }
#undef STAGE_HALF

  // Epilogue. D layout per 16x16 tile: row = g*4 + jj, col = r15.
  const bool doRelu = (i0 < reluRows);
#pragma unroll
  for (int fm = 0; fm < 8; ++fm) {
    const int r0 = i0 + wm * 128 + fm * 16 + g * 4;
#pragma unroll
    for (int fn = 0; fn < 4; ++fn) {
      const int cc = j0 + wn * 64 + fn * 16 + r15;
      const float bv = bias ? bias[cc] : 0.0f;
#pragma unroll
      for (int jj = 0; jj < 4; ++jj) {
        float v = acc[fm][fn][jj] + bv;
        if (doRelu) v = fmaxf(v, 0.0f);
        Co[(long)(r0 + jj) * LDC + cc] = (CO)v;
      }
    }
  }
}

// ---------------------------------------------------------------------------
// K2: per (b,h) n-chunk s (512 cols): partial ctx[d,e] += V[d,n]*K[e,n],
//     partial ksum[e] += K[e,n].  Direct global->MFMA (no LDS), deterministic.
// ---------------------------------------------------------------------------
__global__ __launch_bounds__(256) void ctx_kernel(const bf16* __restrict__ QKV,
                                                  float* __restrict__ ctx_part,
                                                  float* __restrict__ ksum_part) {
  const int bh = blockIdx.x;  // 0..63
  const int s  = blockIdx.y;  // 0..7
  const int b  = bh >> 4, h = bh & 15;
  const int tid = threadIdx.x, lane = tid & 63, w = tid >> 6;
  const long ldq = 16384;
  const bf16* Kp = QKV + (long)(1024 + h * 64) * ldq + b * 4096 + s * 512;
  const bf16* Vp = QKV + (long)(2048 + h * 64) * ldq + b * 4096 + s * 512;

  const int r15  = lane & 15;
  const int koff = (lane >> 4) * 8;

  f32x4 acc[4] = {};  // wave w owns d rows [w*16, w*16+16), 4 e-tiles
#pragma unroll 4
  for (int n = 0; n < 512; n += 32) {
    const bf16x8 a = *(const bf16x8*)(Vp + (long)(w * 16 + r15) * ldq + n + koff);
#pragma unroll
    for (int u = 0; u < 4; ++u) {
      const bf16x8 kb = *(const bf16x8*)(Kp + (long)(u * 16 + r15) * ldq + n + koff);
      acc[u] = MFMA16(a, kb, acc[u]);
    }
  }
  float* cp = ctx_part + (long)(bh * 8 + s) * 4096;
#pragma unroll
  for (int u = 0; u < 4; ++u)
#pragma unroll
    for (int jj = 0; jj < 4; ++jj) {
      const int d = w * 16 + (lane >> 4) * 4 + jj;
      const int e = u * 16 + r15;
      cp[d * 64 + e] = acc[u][jj];
    }

  // ksum partial: 4 threads per e-row, 128 cols each
  const int e = tid >> 2, q4 = tid & 3;
  const bf16* kr = Kp + (long)e * ldq + q4 * 128;
  float sum = 0.0f;
#pragma unroll
  for (int i = 0; i < 128; i += 8) {
    const bf16x8 v = *(const bf16x8*)(kr + i);
#pragma unroll
    for (int jj = 0; jj < 8; ++jj) sum += (float)v[jj];
  }
  sum += __shfl_xor(sum, 1);
  sum += __shfl_xor(sum, 2);
  if (q4 == 0) ksum_part[(bh * 8 + s) * 64 + e] = sum;
}

// ---------------------------------------------------------------------------
// K3: per (b,h), 256-col n-chunk: O[(b,n), h*64+d] = z[n]*sum_e ctx[d,e]Q[e,n]
// ---------------------------------------------------------------------------
__global__ __launch_bounds__(256) void out_kernel(const bf16* __restrict__ QKV,
                                                  const float* __restrict__ ctx_part,
                                                  const float* __restrict__ ksum_part,
                                                  bf16* __restrict__ O) {
  __shared__ bf16 ctx_lds[64 * 88];   // [d][e], stride 88 (176B, 16B-mult, ~2-way)
  __shared__ bf16 qlds[256 * 80];     // [n_local][e], stride 80 (160B, 16B-mult)
  __shared__ float ksum_lds[64];
  __shared__ float zlds[256];

  const int nc = blockIdx.x;  // 0..15
  const int bh = blockIdx.y;  // 0..63
  const int b = bh >> 4, h = bh & 15;
  const int tid = threadIdx.x, lane = tid & 63, w = tid >> 6;
  const int n0 = nc * 256;
  const long ldq = 16384;

  // 1) sum 8 ctx partials -> bf16 LDS
  const float* cp = ctx_part + (long)bh * 8 * 4096;
#pragma unroll
  for (int r = 0; r < 16; ++r) {
    const int idx = tid + r * 256;  // = d*64 + e
    float v = 0.0f;
#pragma unroll
    for (int s2 = 0; s2 < 8; ++s2) v += cp[s2 * 4096 + idx];
    ctx_lds[(idx >> 6) * 88 + (idx & 63)] = (bf16)v;
  }
  if (tid < 64) {
    float v = 0.0f;
#pragma unroll
    for (int s2 = 0; s2 < 8; ++s2) v += ksum_part[(bh * 8 + s2) * 64 + tid];
    ksum_lds[tid] = v;
  }
  // 2) stage Q tile transposed: qlds[n][e]
  {
    const bf16* Qp = QKV + (long)(h * 64) * ldq + b * 4096 + n0;
    const int e = tid >> 2, seg = tid & 3;
    const bf16* qr = Qp + (long)e * ldq + seg * 64;
#pragma unroll
    for (int i = 0; i < 64; i += 8) {
      const bf16x8 v = *(const bf16x8*)(qr + i);
#pragma unroll
      for (int jj = 0; jj < 8; ++jj) qlds[(seg * 64 + i + jj) * 80 + e] = v[jj];
    }
  }
  __syncthreads();

  // 3) z[n] = 1/(ksum . Q[:,n] + eps)
  {
    float a = 0.0f;
    const bf16* qrow = qlds + tid * 80;
#pragma unroll
    for (int d = 0; d < 64; ++d) a += (float)qrow[d] * ksum_lds[d];
    zlds[tid] = 1.0f / (a + 1.1920929e-07f);
  }
  // A-frags (ctx) once per wave: 4 d-tiles x 2 k(e)-steps
  const int r15 = lane & 15;
  const int koff = (lane >> 4) * 8;
  bf16x8 afr[4][2];
#pragma unroll
  for (int t = 0; t < 4; ++t)
#pragma unroll
    for (int s2 = 0; s2 < 2; ++s2)
      afr[t][s2] = *(const bf16x8*)(ctx_lds + (t * 16 + r15) * 88 + s2 * 32 + koff);
  __syncthreads();

  // 4) each wave: 4 n-tiles of 16
#pragma unroll
  for (int nt = 0; nt < 4; ++nt) {
    const int ntile = w * 4 + nt;
    bf16x8 bfr[2];
#pragma unroll
    for (int s2 = 0; s2 < 2; ++s2)
      bfr[s2] = *(const bf16x8*)(qlds + (ntile * 16 + r15) * 80 + s2 * 32 + koff);
    f32x4 accn[4] = {};
#pragma unroll
    for (int t = 0; t < 4; ++t) {
      accn[t] = MFMA16(afr[t][0], bfr[0], accn[t]);
      accn[t] = MFMA16(afr[t][1], bfr[1], accn[t]);
    }
    const int ncol = n0 + ntile * 16 + r15;
    const float zv = zlds[ntile * 16 + r15];
    bf16* orow = O + (long)(b * 4096 + ncol) * 1024 + h * 64;
#pragma unroll
    for (int t = 0; t < 4; ++t) {
      const int d0 = t * 16 + (lane >> 4) * 4;
      bf16x4 pk;
#pragma unroll
      for (int jj = 0; jj < 4; ++jj) pk[jj] = (bf16)(accn[t][jj] * zv);
      *(bf16x4*)(orow + d0) = pk;  // 8B store, 4 consecutive d
    }
  }
}

// ---------------------------------------------------------------------------
extern "C" void kernel_launch(void* const* d_in, const int* in_sizes, int n_in,
                              void* d_out, int out_size, void* d_ws, size_t ws_size,
                              hipStream_t stream) {
  const float* x      = (const float*)d_in[0];  // [4,4096,1024] fp32
  const float* w_qkv  = (const float*)d_in[1];  // [3072,1024]   fp32
  const float* w_proj = (const float*)d_in[2];  // [1024,1024]   fp32
  const float* b_proj = (const float*)d_in[3];  // [1024]        fp32
  float* out = (float*)d_out;                   // [4,4096,1024] fp32

  char* ws = (char*)d_ws;
  // Layout (xb region reused for O after K1):
  bf16*  QKV       = (bf16*)ws;                               // 96 MiB
  float* ctx_part  = (float*)(ws + 100663296);                // 8 MiB
  float* ksum_part = (float*)(ws + 100663296 + 8388608);      // 128 KiB
  bf16*  xb        = (bf16*)(ws + 109182976);                 // 32 MiB (K1 input)
  bf16*  O         = xb;                                      // reuse after K1
  bf16*  wqkvb     = (bf16*)(ws + 109182976 + 33554432);      // 6 MiB
  bf16*  wprojb    = (bf16*)(ws + 109182976 + 33554432 + 6291456);  // 2 MiB

  // K0: fp32 -> bf16 conversions
  cvt_f32_bf16<<<2048, 256, 0, stream>>>(x,      xb,     16777216);
  cvt_f32_bf16<<<512,  256, 0, stream>>>(w_qkv,  wqkvb,  3145728);
  cvt_f32_bf16<<<256,  256, 0, stream>>>(w_proj, wprojb, 1048576);
  // K1: QKV^T[c,m] = sum_k w_qkv[c,k]*x[m,k]; relu rows c<2048. M=3072, N=16384.
  gemm256<16384, bf16><<<dim3(64, 12), 512, 0, stream>>>(wqkvb, xb, QKV, nullptr, 2048);
  // K2: partial ctx + ksum
  ctx_kernel<<<dim3(64, 8), 256, 0, stream>>>(QKV, ctx_part, ksum_part);
  // K3: O[m, c]  (overwrites xb region — xb dead after K1)
  out_kernel<<<dim3(16, 64), 256, 0, stream>>>(QKV, ctx_part, ksum_part, O);
  // K4: out[m,co] = sum_c O[m,c]*w_proj[co,c] + b_proj. M=16384, N=1024, fp32 out.
  gemm256<1024, float><<<dim3(4, 64), 512, 0, stream>>>(O, wprojb, out, b_proj, 0);
}

// Round 6
// 266.632 us; speedup vs baseline: 1.0218x; 1.0218x over previous
//
#include <hip/hip_runtime.h>
#include <hip/hip_bf16.h>

// LinearAttention on MI355X (gfx950). Inputs/outputs fp32; internal bf16 MFMA.
// B=4 N=4096 C=1024 H=16 D=64.
//  K0 cvt3:           xb/wqkvb/wprojb = bf16(x / w_qkv / w_proj)   (one kernel)
//  K1 gemm_bt<16384>: QKV^T[c,m] = sum_k w_qkv[c,k]*x[m,k], relu c<2048 rows.
//                     m97 128x128 structure (proven 750 TF here) + T1 XCD swizzle.
//  K2 ctx_kernel:     per (b,h,s): partial ctx[d,e] = sum_n V[d,n]K[e,n], partial ksum.
//  K3 out_kernel:     O[m, h*64+d] = z[n] * sum_e ctx[d,e] Q[e,n]   (bf16)
//  K4 gemm256<1024>:  out[m,co] = sum_c O[m,c] w_proj[co,c] + b_proj[co]  (fp32)
//                     256x256 2-phase dbuf (measured ~25 us for this shape).
// Deterministic: no atomics; every ws region fully written before read.

typedef __bf16 bf16;
typedef __bf16 bf16x8 __attribute__((ext_vector_type(8)));
typedef __bf16 bf16x4 __attribute__((ext_vector_type(4)));
typedef float  f32x4  __attribute__((ext_vector_type(4)));

#define MFMA16(a, b, c) __builtin_amdgcn_mfma_f32_16x16x32_bf16((a), (b), (c), 0, 0, 0)

__device__ __forceinline__ void gload_lds16(const bf16* g, bf16* l) {
  // 16B per lane; LDS dest = wave-uniform base + lane*16 (linear layout required).
  __builtin_amdgcn_global_load_lds(
      (const __attribute__((address_space(1))) void*)g,
      (__attribute__((address_space(3))) void*)l, 16, 0, 0);
}

// ---------------------------------------------------------------------------
// K0: fused fp32 -> bf16 convert of x (4194304 f4), w_qkv (786432 f4),
//     w_proj (262144 f4). Grid-stride over the 5242880-f4 virtual concat.
// ---------------------------------------------------------------------------
__global__ __launch_bounds__(256) void cvt3(const float* __restrict__ x,  bf16* __restrict__ xb,
                                            const float* __restrict__ wq, bf16* __restrict__ wqb,
                                            const float* __restrict__ wp, bf16* __restrict__ wpb) {
  const long stride = (long)gridDim.x * 256;
  for (long i4 = (long)blockIdx.x * 256 + threadIdx.x; i4 < 5242880; i4 += stride) {
    const float* s; bf16* d; long off;
    if (i4 < 4194304)      { s = x;  d = xb;  off = i4; }
    else if (i4 < 4980736) { s = wq; d = wqb; off = i4 - 4194304; }
    else                   { s = wp; d = wpb; off = i4 - 4980736; }
    const float4 v = *(const float4*)(s + off * 4);
    bf16x4 o;
    o[0] = (bf16)v.x; o[1] = (bf16)v.y; o[2] = (bf16)v.z; o[3] = (bf16)v.w;
    *(bf16x4*)(d + off * 4) = o;
  }
}

// ---------------------------------------------------------------------------
// K1: C[i,j] = sum_k A[i,k]*B[j,k]  (m97 structure: 128x128 tile, BK=32,
// 4 waves 2x2, global_load_lds w16). + T1 chunked-bijective XCD swizzle.
// Grid dim3(N/128, M/128); requires (gx*gy)%8==0 for the swizzle branch.
// ---------------------------------------------------------------------------
template <int LDC, typename CO>
__global__ __launch_bounds__(256) void gemm_bt(const bf16* __restrict__ A,
                                               const bf16* __restrict__ Bm,
                                               CO* __restrict__ Co,
                                               const float* __restrict__ bias,
                                               const int reluRows) {
  __shared__ bf16 As[128 * 32];
  __shared__ bf16 Bs[128 * 32];
  const int tid  = threadIdx.x;
  const int lane = tid & 63;
  const int w    = tid >> 6;        // wave 0..3
  const int wr   = w >> 1;          // 2x2 wave grid
  const int wc   = w & 1;

  // T1: per-XCD contiguous chunk; consecutive sid share the A-row panel.
  const int gx = gridDim.x, gy = gridDim.y;
  const int nwg = gx * gy;
  const int id  = blockIdx.x + gx * blockIdx.y;
  const int sid = (nwg & 7) ? id : ((id & 7) * (nwg >> 3) + (id >> 3));
  const int j0 = (sid % gx) * 128;  // B-row block
  const int i0 = (sid / gx) * 128;  // A-row block

  // staging: per wave 2 instructions per tile, 16 rows (4 lanes/row) each
  const int srow = lane >> 2;
  const int scol = (lane & 3) * 8;
  const bf16* Ag = A  + (long)(i0 + w * 32 + srow) * 1024 + scol;
  const bf16* Bg = Bm + (long)(j0 + w * 32 + srow) * 1024 + scol;
  bf16* Asw = As + w * 32 * 32;
  bf16* Bsw = Bs + w * 32 * 32;

  const int r15  = lane & 15;
  const int koff = (lane >> 4) * 8;

  f32x4 acc[4][4] = {};

  for (int kk = 0; kk < 1024; kk += 32) {
    gload_lds16(Ag + kk,             Asw);
    gload_lds16(Ag + kk + 16 * 1024, Asw + 16 * 32);
    gload_lds16(Bg + kk,             Bsw);
    gload_lds16(Bg + kk + 16 * 1024, Bsw + 16 * 32);
    __syncthreads();  // drains vmcnt (compiler emits waitcnt before s_barrier)
    bf16x8 af[4], bfm[4];
#pragma unroll
    for (int t = 0; t < 4; ++t)
      af[t] = *(const bf16x8*)(As + (wr * 64 + t * 16 + r15) * 32 + koff);
#pragma unroll
    for (int u = 0; u < 4; ++u)
      bfm[u] = *(const bf16x8*)(Bs + (wc * 64 + u * 16 + r15) * 32 + koff);
#pragma unroll
    for (int t = 0; t < 4; ++t)
#pragma unroll
      for (int u = 0; u < 4; ++u)
        acc[t][u] = MFMA16(af[t], bfm[u], acc[t][u]);
    __syncthreads();
  }

  // D layout per 16x16 tile: row = (lane>>4)*4 + jj, col = lane&15
  const bool doRelu = (i0 < reluRows);  // block-uniform (128 | reluRows)
  const int rbase = i0 + wr * 64;
  const int cbase = j0 + wc * 64;
#pragma unroll
  for (int t = 0; t < 4; ++t) {
    const int r0 = rbase + t * 16 + (lane >> 4) * 4;
#pragma unroll
    for (int u = 0; u < 4; ++u) {
      const int cc = cbase + u * 16 + r15;
      const float bv = bias ? bias[cc] : 0.0f;
#pragma unroll
      for (int jj = 0; jj < 4; ++jj) {
        float v = acc[t][u][jj] + bv;
        if (doRelu) v = fmaxf(v, 0.0f);
        Co[(long)(r0 + jj) * LDC + cc] = (CO)v;
      }
    }
  }
}

// ---------------------------------------------------------------------------
// K4: gemm256 (R4 2-phase dbuf version, verified): C[i,j]=sum_k A[i,k]*B[j,k].
// 256x256 tile, BK=64, 8 waves, counted vmcnt(8) prefetch, XOR-swizzled LDS,
// setprio, XCD swizzle. Grid dim3(N/256, M/256), 512 threads.
// ---------------------------------------------------------------------------
template <int LDC, typename CO>
__global__ __launch_bounds__(512, 2) void gemm256(const bf16* __restrict__ A,
                                                  const bf16* __restrict__ Bm,
                                                  CO* __restrict__ Co,
                                                  const float* __restrict__ bias,
                                                  const int reluRows) {
  __shared__ bf16 As[2][256 * 64];
  __shared__ bf16 Bs[2][256 * 64];
  const int tid  = threadIdx.x;
  const int lane = tid & 63;
  const int w    = tid >> 6;      // wave 0..7
  const int wm   = w >> 2;        // 2 M-halves
  const int wn   = w & 3;         // 4 N-quarters

  const int gx = gridDim.x, gy = gridDim.y;
  const int nwg = gx * gy;
  const int id  = blockIdx.x + gx * blockIdx.y;
  const int sid = (id & 7) * (nwg >> 3) + (id >> 3);
  int bx, by;
  if (gx < gy) { bx = sid % gx; by = sid / gx; }
  else         { by = sid % gy; bx = sid / gy; }
  const int i0 = by * 256;
  const int j0 = bx * 256;

  // staging: lane l -> row lr = l>>3, 16B-chunk lc = (l&7)^lr (pre-swizzled
  // global source so that linear LDS holds the XOR-swizzled layout).
  const int lr = lane >> 3;
  const int lc = (lane & 7) ^ lr;
  const bf16* Agl = A  + (long)(i0 + 8 * w + lr) * 1024 + lc * 8;
  const bf16* Bgl = Bm + (long)(j0 + 8 * w + lr) * 1024 + lc * 8;
  const int wofs = w * 512;  // (8w rows) * 64 elems

  // ds_read: logical (row, chunk c) at byte row*128 + (c^(row&7))*16.
  const int r15 = lane & 15, g = lane >> 4;
  const int ck[2] = { ((0 + g) ^ (r15 & 7)) * 8, ((4 + g) ^ (r15 & 7)) * 8 };
  const int arow = (wm * 128 + r15) * 64;
  const int brow = (wn * 64 + r15) * 64;

  f32x4 acc[8][4] = {};

#pragma unroll
  for (int q = 0; q < 4; ++q) {
    gload_lds16(Agl + q * 65536, &As[0][q * 4096 + wofs]);
    gload_lds16(Bgl + q * 65536, &Bs[0][q * 4096 + wofs]);
  }

  for (int kt = 0; kt < 16; ++kt) {
    const int cur = kt & 1;
    if (kt < 15) {
      const long ko = (long)(kt + 1) * 64;
#pragma unroll
      for (int q = 0; q < 4; ++q) {
        gload_lds16(Agl + ko + q * 65536, &As[cur ^ 1][q * 4096 + wofs]);
        gload_lds16(Bgl + ko + q * 65536, &Bs[cur ^ 1][q * 4096 + wofs]);
      }
      asm volatile("s_waitcnt vmcnt(8)" ::: "memory");
    } else {
      asm volatile("s_waitcnt vmcnt(0)" ::: "memory");
    }
    __builtin_amdgcn_s_barrier();
    __builtin_amdgcn_sched_barrier(0);

    const bf16* Ab = &As[cur][arow];
    const bf16* Bb = &Bs[cur][brow];
#pragma unroll
    for (int ks = 0; ks < 2; ++ks) {
      bf16x8 af[8], bfr[4];
#pragma unroll
      for (int fm = 0; fm < 8; ++fm)
        af[fm] = *(const bf16x8*)(Ab + fm * 1024 + ck[ks]);
#pragma unroll
      for (int fn = 0; fn < 4; ++fn)
        bfr[fn] = *(const bf16x8*)(Bb + fn * 1024 + ck[ks]);
      __builtin_amdgcn_s_setprio(1);
#pragma unroll
      for (int fm = 0; fm < 8; ++fm)
#pragma unroll
        for (int fn = 0; fn < 4; ++fn)
          acc[fm][fn] = MFMA16(af[fm], bfr[fn], acc[fm][fn]);
      __builtin_amdgcn_s_setprio(0);
    }
    asm volatile("s_waitcnt lgkmcnt(0)" ::: "memory");
    __builtin_amdgcn_sched_barrier(0);
    __builtin_amdgcn_s_barrier();
  }

  const bool doRelu = (i0 < reluRows);
#pragma unroll
  for (int fm = 0; fm < 8; ++fm) {
    const int r0 = i0 + wm * 128 + fm * 16 + g * 4;
#pragma unroll
    for (int fn = 0; fn < 4; ++fn) {
      const int cc = j0 + wn * 64 + fn * 16 + r15;
      const float bv = bias ? bias[cc] : 0.0f;
#pragma unroll
      for (int jj = 0; jj < 4; ++jj) {
        float v = acc[fm][fn][jj] + bv;
        if (doRelu) v = fmaxf(v, 0.0f);
        Co[(long)(r0 + jj) * LDC + cc] = (CO)v;
      }
    }
  }
}

// ---------------------------------------------------------------------------
// K2: per (b,h) n-chunk s (512 cols): partial ctx[d,e] += V[d,n]*K[e,n],
//     partial ksum[e] += K[e,n].  Direct global->MFMA (no LDS), deterministic.
// ---------------------------------------------------------------------------
__global__ __launch_bounds__(256) void ctx_kernel(const bf16* __restrict__ QKV,
                                                  float* __restrict__ ctx_part,
                                                  float* __restrict__ ksum_part) {
  const int bh = blockIdx.x;  // 0..63
  const int s  = blockIdx.y;  // 0..7
  const int b  = bh >> 4, h = bh & 15;
  const int tid = threadIdx.x, lane = tid & 63, w = tid >> 6;
  const long ldq = 16384;
  const bf16* Kp = QKV + (long)(1024 + h * 64) * ldq + b * 4096 + s * 512;
  const bf16* Vp = QKV + (long)(2048 + h * 64) * ldq + b * 4096 + s * 512;

  const int r15  = lane & 15;
  const int koff = (lane >> 4) * 8;

  f32x4 acc[4] = {};  // wave w owns d rows [w*16, w*16+16), 4 e-tiles
#pragma unroll 4
  for (int n = 0; n < 512; n += 32) {
    const bf16x8 a = *(const bf16x8*)(Vp + (long)(w * 16 + r15) * ldq + n + koff);
#pragma unroll
    for (int u = 0; u < 4; ++u) {
      const bf16x8 kb = *(const bf16x8*)(Kp + (long)(u * 16 + r15) * ldq + n + koff);
      acc[u] = MFMA16(a, kb, acc[u]);
    }
  }
  float* cp = ctx_part + (long)(bh * 8 + s) * 4096;
#pragma unroll
  for (int u = 0; u < 4; ++u)
#pragma unroll
    for (int jj = 0; jj < 4; ++jj) {
      const int d = w * 16 + (lane >> 4) * 4 + jj;
      const int e = u * 16 + r15;
      cp[d * 64 + e] = acc[u][jj];
    }

  // ksum partial: 4 threads per e-row, 128 cols each
  const int e = tid >> 2, q4 = tid & 3;
  const bf16* kr = Kp + (long)e * ldq + q4 * 128;
  float sum = 0.0f;
#pragma unroll
  for (int i = 0; i < 128; i += 8) {
    const bf16x8 v = *(const bf16x8*)(kr + i);
#pragma unroll
    for (int jj = 0; jj < 8; ++jj) sum += (float)v[jj];
  }
  sum += __shfl_xor(sum, 1);
  sum += __shfl_xor(sum, 2);
  if (q4 == 0) ksum_part[(bh * 8 + s) * 64 + e] = sum;
}

// ---------------------------------------------------------------------------
// K3: per (b,h), 256-col n-chunk: O[(b,n), h*64+d] = z[n]*sum_e ctx[d,e]Q[e,n]
// ---------------------------------------------------------------------------
__global__ __launch_bounds__(256) void out_kernel(const bf16* __restrict__ QKV,
                                                  const float* __restrict__ ctx_part,
                                                  const float* __restrict__ ksum_part,
                                                  bf16* __restrict__ O) {
  __shared__ bf16 ctx_lds[64 * 88];   // [d][e], stride 88 (176B, 16B-mult, ~2-way)
  __shared__ bf16 qlds[256 * 80];     // [n_local][e], stride 80 (160B, 16B-mult)
  __shared__ float ksum_lds[64];
  __shared__ float zlds[256];

  const int nc = blockIdx.x;  // 0..15
  const int bh = blockIdx.y;  // 0..63
  const int b = bh >> 4, h = bh & 15;
  const int tid = threadIdx.x, lane = tid & 63, w = tid >> 6;
  const int n0 = nc * 256;
  const long ldq = 16384;

  // 1) sum 8 ctx partials -> bf16 LDS
  const float* cp = ctx_part + (long)bh * 8 * 4096;
#pragma unroll
  for (int r = 0; r < 16; ++r) {
    const int idx = tid + r * 256;  // = d*64 + e
    float v = 0.0f;
#pragma unroll
    for (int s2 = 0; s2 < 8; ++s2) v += cp[s2 * 4096 + idx];
    ctx_lds[(idx >> 6) * 88 + (idx & 63)] = (bf16)v;
  }
  if (tid < 64) {
    float v = 0.0f;
#pragma unroll
    for (int s2 = 0; s2 < 8; ++s2) v += ksum_part[(bh * 8 + s2) * 64 + tid];
    ksum_lds[tid] = v;
  }
  // 2) stage Q tile transposed: qlds[n][e]
  {
    const bf16* Qp = QKV + (long)(h * 64) * ldq + b * 4096 + n0;
    const int e = tid >> 2, seg = tid & 3;
    const bf16* qr = Qp + (long)e * ldq + seg * 64;
#pragma unroll
    for (int i = 0; i < 64; i += 8) {
      const bf16x8 v = *(const bf16x8*)(qr + i);
#pragma unroll
      for (int jj = 0; jj < 8; ++jj) qlds[(seg * 64 + i + jj) * 80 + e] = v[jj];
    }
  }
  __syncthreads();

  // 3) z[n] = 1/(ksum . Q[:,n] + eps)
  {
    float a = 0.0f;
    const bf16* qrow = qlds + tid * 80;
#pragma unroll
    for (int d = 0; d < 64; ++d) a += (float)qrow[d] * ksum_lds[d];
    zlds[tid] = 1.0f / (a + 1.1920929e-07f);
  }
  // A-frags (ctx) once per wave: 4 d-tiles x 2 k(e)-steps
  const int r15 = lane & 15;
  const int koff = (lane >> 4) * 8;
  bf16x8 afr[4][2];
#pragma unroll
  for (int t = 0; t < 4; ++t)
#pragma unroll
    for (int s2 = 0; s2 < 2; ++s2)
      afr[t][s2] = *(const bf16x8*)(ctx_lds + (t * 16 + r15) * 88 + s2 * 32 + koff);
  __syncthreads();

  // 4) each wave: 4 n-tiles of 16
#pragma unroll
  for (int nt = 0; nt < 4; ++nt) {
    const int ntile = w * 4 + nt;
    bf16x8 bfr[2];
#pragma unroll
    for (int s2 = 0; s2 < 2; ++s2)
      bfr[s2] = *(const bf16x8*)(qlds + (ntile * 16 + r15) * 80 + s2 * 32 + koff);
    f32x4 accn[4] = {};
#pragma unroll
    for (int t = 0; t < 4; ++t) {
      accn[t] = MFMA16(afr[t][0], bfr[0], accn[t]);
      accn[t] = MFMA16(afr[t][1], bfr[1], accn[t]);
    }
    const int ncol = n0 + ntile * 16 + r15;
    const float zv = zlds[ntile * 16 + r15];
    bf16* orow = O + (long)(b * 4096 + ncol) * 1024 + h * 64;
#pragma unroll
    for (int t = 0; t < 4; ++t) {
      const int d0 = t * 16 + (lane >> 4) * 4;
      bf16x4 pk;
#pragma unroll
      for (int jj = 0; jj < 4; ++jj) pk[jj] = (bf16)(accn[t][jj] * zv);
      *(bf16x4*)(orow + d0) = pk;  // 8B store, 4 consecutive d
    }
  }
}

// ---------------------------------------------------------------------------
extern "C" void kernel_launch(void* const* d_in, const int* in_sizes, int n_in,
                              void* d_out, int out_size, void* d_ws, size_t ws_size,
                              hipStream_t stream) {
  const float* x      = (const float*)d_in[0];  // [4,4096,1024] fp32
  const float* w_qkv  = (const float*)d_in[1];  // [3072,1024]   fp32
  const float* w_proj = (const float*)d_in[2];  // [1024,1024]   fp32
  const float* b_proj = (const float*)d_in[3];  // [1024]        fp32
  float* out = (float*)d_out;                   // [4,4096,1024] fp32

  char* ws = (char*)d_ws;
  // Layout (xb region reused for O after K1):
  bf16*  QKV       = (bf16*)ws;                               // 96 MiB
  float* ctx_part  = (float*)(ws + 100663296);                // 8 MiB
  float* ksum_part = (float*)(ws + 100663296 + 8388608);      // 128 KiB
  bf16*  xb        = (bf16*)(ws + 109182976);                 // 32 MiB (K1 input)
  bf16*  O         = xb;                                      // reuse after K1
  bf16*  wqkvb     = (bf16*)(ws + 109182976 + 33554432);      // 6 MiB
  bf16*  wprojb    = (bf16*)(ws + 109182976 + 33554432 + 6291456);  // 2 MiB

  // K0: fused fp32 -> bf16 conversions
  cvt3<<<2048, 256, 0, stream>>>(x, xb, w_qkv, wqkvb, w_proj, wprojb);
  // K1: QKV^T[c,m] = sum_k w_qkv[c,k]*x[m,k]; relu rows c<2048. M=3072, N=16384.
  gemm_bt<16384, bf16><<<dim3(128, 24), 256, 0, stream>>>(wqkvb, xb, QKV, nullptr, 2048);
  // K2: partial ctx + ksum
  ctx_kernel<<<dim3(64, 8), 256, 0, stream>>>(QKV, ctx_part, ksum_part);
  // K3: O[m, c]  (overwrites xb region — xb dead after K1)
  out_kernel<<<dim3(16, 64), 256, 0, stream>>>(QKV, ctx_part, ksum_part, O);
  // K4: out[m,co] = sum_c O[m,c]*w_proj[co,c] + b_proj. M=16384, N=1024, fp32 out.
  gemm256<1024, float><<<dim3(4, 64), 512, 0, stream>>>(O, wprojb, out, b_proj, 0);
}

// Round 7
// 254.698 us; speedup vs baseline: 1.0696x; 1.0469x over previous
//
#include <hip/hip_runtime.h>
#include <hip/hip_bf16.h>

// LinearAttention on MI355X (gfx950). Inputs/outputs fp32; internal bf16 MFMA.
// B=4 N=4096 C=1024 H=16 D=64.
//  K0 cvt3:           xb/wqkvb/wprojb = bf16(x / w_qkv / w_proj)   (one kernel)
//  K1 gemm_bt64:      QKV^T[c,m] = sum_k w_qkv[c,k]*x[m,k], relu c<2048 rows.
//                     m97 structure, BK=64, XOR-swizzled LDS (both-sides),
//                     NATURAL block order (same-j blocks share an XCD's L2 —
//                     measured R6: chunked swizzle quadrupled FETCH_SIZE).
//  K2 ctx_kernel:     per (b,h,s): partial ctx[d,e] = sum_n V[d,n]K[e,n], + ksum.
//  K3 out_kernel:     O[m, h*64+d] = z[n] * sum_e ctx[d,e] Q[e,n]   (bf16)
//  K4 gemm256<1024>:  out[m,co] = sum_c O[m,c] w_proj[co,c] + b_proj[co] (fp32)
// Deterministic: no atomics; every ws region fully written before read.

typedef __bf16 bf16;
typedef __bf16 bf16x8 __attribute__((ext_vector_type(8)));
typedef __bf16 bf16x4 __attribute__((ext_vector_type(4)));
typedef float  f32x4  __attribute__((ext_vector_type(4)));

#define MFMA16(a, b, c) __builtin_amdgcn_mfma_f32_16x16x32_bf16((a), (b), (c), 0, 0, 0)

__device__ __forceinline__ void gload_lds16(const bf16* g, bf16* l) {
  // 16B per lane; LDS dest = wave-uniform base + lane*16 (linear layout required).
  __builtin_amdgcn_global_load_lds(
      (const __attribute__((address_space(1))) void*)g,
      (__attribute__((address_space(3))) void*)l, 16, 0, 0);
}

// ---------------------------------------------------------------------------
// K0: fused fp32 -> bf16 convert of x (4194304 f4), w_qkv (786432 f4),
//     w_proj (262144 f4). Grid-stride over the 5242880-f4 virtual concat.
// ---------------------------------------------------------------------------
__global__ __launch_bounds__(256) void cvt3(const float* __restrict__ x,  bf16* __restrict__ xb,
                                            const float* __restrict__ wq, bf16* __restrict__ wqb,
                                            const float* __restrict__ wp, bf16* __restrict__ wpb) {
  const long stride = (long)gridDim.x * 256;
  for (long i4 = (long)blockIdx.x * 256 + threadIdx.x; i4 < 5242880; i4 += stride) {
    const float* s; bf16* d; long off;
    if (i4 < 4194304)      { s = x;  d = xb;  off = i4; }
    else if (i4 < 4980736) { s = wq; d = wqb; off = i4 - 4194304; }
    else                   { s = wp; d = wpb; off = i4 - 4980736; }
    const float4 v = *(const float4*)(s + off * 4);
    bf16x4 o;
    o[0] = (bf16)v.x; o[1] = (bf16)v.y; o[2] = (bf16)v.z; o[3] = (bf16)v.w;
    *(bf16x4*)(d + off * 4) = o;
  }
}

// ---------------------------------------------------------------------------
// K1: C[i,j] = sum_k A[i,k]*B[j,k]  — m97 2-barrier structure, BK=64,
// 128x128 tile, 4 waves (2x2), global_load_lds w16, XOR chunk swizzle:
// logical 16B-chunk c of row r lives at phys chunk c^(r&7). Staged via
// pre-swizzled per-lane GLOBAL source + linear LDS dest (rule #21).
// Natural block order (no XCD swizzle — see R6 post-mortem).
// Grid dim3(N/128, M/128).
// ---------------------------------------------------------------------------
template <int LDC, typename CO>
__global__ __launch_bounds__(256) void gemm_bt64(const bf16* __restrict__ A,
                                                 const bf16* __restrict__ Bm,
                                                 CO* __restrict__ Co,
                                                 const float* __restrict__ bias,
                                                 const int reluRows) {
  __shared__ bf16 As[128 * 64];
  __shared__ bf16 Bs[128 * 64];
  const int tid  = threadIdx.x;
  const int lane = tid & 63;
  const int w    = tid >> 6;        // wave 0..3
  const int wr   = w >> 1;          // 2x2 wave grid
  const int wc   = w & 1;
  const int j0 = blockIdx.x * 128;  // B-row block
  const int i0 = blockIdx.y * 128;  // A-row block

  // Staging: wave w rows [32w,32w+32), instr q covers 8 rows; lane l ->
  // row8 = l>>3, pre-swizzled source chunk lc = (l&7)^(l>>3) so that the
  // linear LDS dest (phys chunk = l&7) holds logical chunk c at c^(row&7).
  const int lr8 = lane >> 3;
  const int lc  = (lane & 7) ^ lr8;
  const bf16* Ag = A  + (long)(i0 + w * 32 + lr8) * 1024 + lc * 8;
  const bf16* Bg = Bm + (long)(j0 + w * 32 + lr8) * 1024 + lc * 8;
  bf16* Asw = As + w * 32 * 64;
  bf16* Bsw = Bs + w * 32 * 64;

  const int r15 = lane & 15, g = lane >> 4;
  // frag chunk offsets (elems): ks-block ks, k-group g -> phys chunk (ks*4+g)^(r15&7)
  const int ac0 = ((0 + g) ^ (r15 & 7)) * 8;   // ks=0
  const int ac1 = ((4 + g) ^ (r15 & 7)) * 8;   // ks=1

  f32x4 acc[4][4] = {};

  for (int kk = 0; kk < 1024; kk += 64) {
#pragma unroll
    for (int q = 0; q < 4; ++q) {
      gload_lds16(Ag + kk + q * 8 * 1024, Asw + q * 512);
      gload_lds16(Bg + kk + q * 8 * 1024, Bsw + q * 512);
    }
    __syncthreads();  // drains vmcnt before barrier (compiler-emitted)
    bf16x8 af[4][2], bfm[4][2];
#pragma unroll
    for (int t = 0; t < 4; ++t) {
      const int ra = (wr * 64 + t * 16 + r15) * 64;
      af[t][0] = *(const bf16x8*)(As + ra + ac0);
      af[t][1] = *(const bf16x8*)(As + ra + ac1);
      const int rb = (wc * 64 + t * 16 + r15) * 64;
      bfm[t][0] = *(const bf16x8*)(Bs + rb + ac0);
      bfm[t][1] = *(const bf16x8*)(Bs + rb + ac1);
    }
#pragma unroll
    for (int ks = 0; ks < 2; ++ks)
#pragma unroll
      for (int t = 0; t < 4; ++t)
#pragma unroll
        for (int u = 0; u < 4; ++u)
          acc[t][u] = MFMA16(af[t][ks], bfm[u][ks], acc[t][u]);
    __syncthreads();
  }

  // D layout per 16x16 tile: row = g*4 + jj, col = r15
  const bool doRelu = (i0 < reluRows);  // block-uniform (128 | reluRows)
  const int rbase = i0 + wr * 64;
  const int cbase = j0 + wc * 64;
#pragma unroll
  for (int t = 0; t < 4; ++t) {
    const int r0 = rbase + t * 16 + g * 4;
#pragma unroll
    for (int u = 0; u < 4; ++u) {
      const int cc = cbase + u * 16 + r15;
      const float bv = bias ? bias[cc] : 0.0f;
#pragma unroll
      for (int jj = 0; jj < 4; ++jj) {
        float v = acc[t][u][jj] + bv;
        if (doRelu) v = fmaxf(v, 0.0f);
        Co[(long)(r0 + jj) * LDC + cc] = (CO)v;
      }
    }
  }
}

// ---------------------------------------------------------------------------
// K4: gemm256 (2-phase dbuf, verified R4/R6): C[i,j]=sum_k A[i,k]*B[j,k].
// 256x256 tile, BK=64, 8 waves, counted vmcnt(8) prefetch, XOR-swizzled LDS,
// setprio, XCD swizzle. Grid dim3(N/256, M/256), 512 threads.
// ---------------------------------------------------------------------------
template <int LDC, typename CO>
__global__ __launch_bounds__(512, 2) void gemm256(const bf16* __restrict__ A,
                                                  const bf16* __restrict__ Bm,
                                                  CO* __restrict__ Co,
                                                  const float* __restrict__ bias,
                                                  const int reluRows) {
  __shared__ bf16 As[2][256 * 64];
  __shared__ bf16 Bs[2][256 * 64];
  const int tid  = threadIdx.x;
  const int lane = tid & 63;
  const int w    = tid >> 6;      // wave 0..7
  const int wm   = w >> 2;        // 2 M-halves
  const int wn   = w & 3;         // 4 N-quarters

  const int gx = gridDim.x, gy = gridDim.y;
  const int nwg = gx * gy;
  const int id  = blockIdx.x + gx * blockIdx.y;
  const int sid = (id & 7) * (nwg >> 3) + (id >> 3);
  int bx, by;
  if (gx < gy) { bx = sid % gx; by = sid / gx; }
  else         { by = sid % gy; bx = sid / gy; }
  const int i0 = by * 256;
  const int j0 = bx * 256;

  const int lr = lane >> 3;
  const int lc = (lane & 7) ^ lr;
  const bf16* Agl = A  + (long)(i0 + 8 * w + lr) * 1024 + lc * 8;
  const bf16* Bgl = Bm + (long)(j0 + 8 * w + lr) * 1024 + lc * 8;
  const int wofs = w * 512;

  const int r15 = lane & 15, g = lane >> 4;
  const int ck[2] = { ((0 + g) ^ (r15 & 7)) * 8, ((4 + g) ^ (r15 & 7)) * 8 };
  const int arow = (wm * 128 + r15) * 64;
  const int brow = (wn * 64 + r15) * 64;

  f32x4 acc[8][4] = {};

#pragma unroll
  for (int q = 0; q < 4; ++q) {
    gload_lds16(Agl + q * 65536, &As[0][q * 4096 + wofs]);
    gload_lds16(Bgl + q * 65536, &Bs[0][q * 4096 + wofs]);
  }

  for (int kt = 0; kt < 16; ++kt) {
    const int cur = kt & 1;
    if (kt < 15) {
      const long ko = (long)(kt + 1) * 64;
#pragma unroll
      for (int q = 0; q < 4; ++q) {
        gload_lds16(Agl + ko + q * 65536, &As[cur ^ 1][q * 4096 + wofs]);
        gload_lds16(Bgl + ko + q * 65536, &Bs[cur ^ 1][q * 4096 + wofs]);
      }
      asm volatile("s_waitcnt vmcnt(8)" ::: "memory");
    } else {
      asm volatile("s_waitcnt vmcnt(0)" ::: "memory");
    }
    __builtin_amdgcn_s_barrier();
    __builtin_amdgcn_sched_barrier(0);

    const bf16* Ab = &As[cur][arow];
    const bf16* Bb = &Bs[cur][brow];
#pragma unroll
    for (int ks = 0; ks < 2; ++ks) {
      bf16x8 af[8], bfr[4];
#pragma unroll
      for (int fm = 0; fm < 8; ++fm)
        af[fm] = *(const bf16x8*)(Ab + fm * 1024 + ck[ks]);
#pragma unroll
      for (int fn = 0; fn < 4; ++fn)
        bfr[fn] = *(const bf16x8*)(Bb + fn * 1024 + ck[ks]);
      __builtin_amdgcn_s_setprio(1);
#pragma unroll
      for (int fm = 0; fm < 8; ++fm)
#pragma unroll
        for (int fn = 0; fn < 4; ++fn)
          acc[fm][fn] = MFMA16(af[fm], bfr[fn], acc[fm][fn]);
      __builtin_amdgcn_s_setprio(0);
    }
    asm volatile("s_waitcnt lgkmcnt(0)" ::: "memory");
    __builtin_amdgcn_sched_barrier(0);
    __builtin_amdgcn_s_barrier();
  }

  const bool doRelu = (i0 < reluRows);
#pragma unroll
  for (int fm = 0; fm < 8; ++fm) {
    const int r0 = i0 + wm * 128 + fm * 16 + g * 4;
#pragma unroll
    for (int fn = 0; fn < 4; ++fn) {
      const int cc = j0 + wn * 64 + fn * 16 + r15;
      const float bv = bias ? bias[cc] : 0.0f;
#pragma unroll
      for (int jj = 0; jj < 4; ++jj) {
        float v = acc[fm][fn][jj] + bv;
        if (doRelu) v = fmaxf(v, 0.0f);
        Co[(long)(r0 + jj) * LDC + cc] = (CO)v;
      }
    }
  }
}

// ---------------------------------------------------------------------------
// K2: per (b,h) n-chunk s (512 cols): partial ctx[d,e] += V[d,n]*K[e,n],
//     partial ksum[e] += K[e,n].  Direct global->MFMA (no LDS), deterministic.
// ---------------------------------------------------------------------------
__global__ __launch_bounds__(256) void ctx_kernel(const bf16* __restrict__ QKV,
                                                  float* __restrict__ ctx_part,
                                                  float* __restrict__ ksum_part) {
  const int bh = blockIdx.x;  // 0..63
  const int s  = blockIdx.y;  // 0..7
  const int b  = bh >> 4, h = bh & 15;
  const int tid = threadIdx.x, lane = tid & 63, w = tid >> 6;
  const long ldq = 16384;
  const bf16* Kp = QKV + (long)(1024 + h * 64) * ldq + b * 4096 + s * 512;
  const bf16* Vp = QKV + (long)(2048 + h * 64) * ldq + b * 4096 + s * 512;

  const int r15  = lane & 15;
  const int koff = (lane >> 4) * 8;

  f32x4 acc[4] = {};  // wave w owns d rows [w*16, w*16+16), 4 e-tiles
#pragma unroll 4
  for (int n = 0; n < 512; n += 32) {
    const bf16x8 a = *(const bf16x8*)(Vp + (long)(w * 16 + r15) * ldq + n + koff);
#pragma unroll
    for (int u = 0; u < 4; ++u) {
      const bf16x8 kb = *(const bf16x8*)(Kp + (long)(u * 16 + r15) * ldq + n + koff);
      acc[u] = MFMA16(a, kb, acc[u]);
    }
  }
  float* cp = ctx_part + (long)(bh * 8 + s) * 4096;
#pragma unroll
  for (int u = 0; u < 4; ++u)
#pragma unroll
    for (int jj = 0; jj < 4; ++jj) {
      const int d = w * 16 + (lane >> 4) * 4 + jj;
      const int e = u * 16 + r15;
      cp[d * 64 + e] = acc[u][jj];
    }

  // ksum partial: 4 threads per e-row, 128 cols each
  const int e = tid >> 2, q4 = tid & 3;
  const bf16* kr = Kp + (long)e * ldq + q4 * 128;
  float sum = 0.0f;
#pragma unroll
  for (int i = 0; i < 128; i += 8) {
    const bf16x8 v = *(const bf16x8*)(kr + i);
#pragma unroll
    for (int jj = 0; jj < 8; ++jj) sum += (float)v[jj];
  }
  sum += __shfl_xor(sum, 1);
  sum += __shfl_xor(sum, 2);
  if (q4 == 0) ksum_part[(bh * 8 + s) * 64 + e] = sum;
}

// ---------------------------------------------------------------------------
// K3: per (b,h), 256-col n-chunk: O[(b,n), h*64+d] = z[n]*sum_e ctx[d,e]Q[e,n]
// ---------------------------------------------------------------------------
__global__ __launch_bounds__(256) void out_kernel(const bf16* __restrict__ QKV,
                                                  const float* __restrict__ ctx_part,
                                                  const float* __restrict__ ksum_part,
                                                  bf16* __restrict__ O) {
  __shared__ bf16 ctx_lds[64 * 88];   // [d][e], stride 88 (176B, 16B-mult, ~2-way)
  __shared__ bf16 qlds[256 * 80];     // [n_local][e], stride 80 (160B, 16B-mult)
  __shared__ float ksum_lds[64];
  __shared__ float zlds[256];

  const int nc = blockIdx.x;  // 0..15
  const int bh = blockIdx.y;  // 0..63
  const int b = bh >> 4, h = bh & 15;
  const int tid = threadIdx.x, lane = tid & 63, w = tid >> 6;
  const int n0 = nc * 256;
  const long ldq = 16384;

  // 1) sum 8 ctx partials -> bf16 LDS
  const float* cp = ctx_part + (long)bh * 8 * 4096;
#pragma unroll
  for (int r = 0; r < 16; ++r) {
    const int idx = tid + r * 256;  // = d*64 + e
    float v = 0.0f;
#pragma unroll
    for (int s2 = 0; s2 < 8; ++s2) v += cp[s2 * 4096 + idx];
    ctx_lds[(idx >> 6) * 88 + (idx & 63)] = (bf16)v;
  }
  if (tid < 64) {
    float v = 0.0f;
#pragma unroll
    for (int s2 = 0; s2 < 8; ++s2) v += ksum_part[(bh * 8 + s2) * 64 + tid];
    ksum_lds[tid] = v;
  }
  // 2) stage Q tile transposed: qlds[n][e]
  {
    const bf16* Qp = QKV + (long)(h * 64) * ldq + b * 4096 + n0;
    const int e = tid >> 2, seg = tid & 3;
    const bf16* qr = Qp + (long)e * ldq + seg * 64;
#pragma unroll
    for (int i = 0; i < 64; i += 8) {
      const bf16x8 v = *(const bf16x8*)(qr + i);
#pragma unroll
      for (int jj = 0; jj < 8; ++jj) qlds[(seg * 64 + i + jj) * 80 + e] = v[jj];
    }
  }
  __syncthreads();

  // 3) z[n] = 1/(ksum . Q[:,n] + eps)
  {
    float a = 0.0f;
    const bf16* qrow = qlds + tid * 80;
#pragma unroll
    for (int d = 0; d < 64; ++d) a += (float)qrow[d] * ksum_lds[d];
    zlds[tid] = 1.0f / (a + 1.1920929e-07f);
  }
  // A-frags (ctx) once per wave: 4 d-tiles x 2 k(e)-steps
  const int r15 = lane & 15;
  const int koff = (lane >> 4) * 8;
  bf16x8 afr[4][2];
#pragma unroll
  for (int t = 0; t < 4; ++t)
#pragma unroll
    for (int s2 = 0; s2 < 2; ++s2)
      afr[t][s2] = *(const bf16x8*)(ctx_lds + (t * 16 + r15) * 88 + s2 * 32 + koff);
  __syncthreads();

  // 4) each wave: 4 n-tiles of 16
#pragma unroll
  for (int nt = 0; nt < 4; ++nt) {
    const int ntile = w * 4 + nt;
    bf16x8 bfr[2];
#pragma unroll
    for (int s2 = 0; s2 < 2; ++s2)
      bfr[s2] = *(const bf16x8*)(qlds + (ntile * 16 + r15) * 80 + s2 * 32 + koff);
    f32x4 accn[4] = {};
#pragma unroll
    for (int t = 0; t < 4; ++t) {
      accn[t] = MFMA16(afr[t][0], bfr[0], accn[t]);
      accn[t] = MFMA16(afr[t][1], bfr[1], accn[t]);
    }
    const int ncol = n0 + ntile * 16 + r15;
    const float zv = zlds[ntile * 16 + r15];
    bf16* orow = O + (long)(b * 4096 + ncol) * 1024 + h * 64;
#pragma unroll
    for (int t = 0; t < 4; ++t) {
      const int d0 = t * 16 + (lane >> 4) * 4;
      bf16x4 pk;
#pragma unroll
      for (int jj = 0; jj < 4; ++jj) pk[jj] = (bf16)(accn[t][jj] * zv);
      *(bf16x4*)(orow + d0) = pk;  // 8B store, 4 consecutive d
    }
  }
}

// ---------------------------------------------------------------------------
extern "C" void kernel_launch(void* const* d_in, const int* in_sizes, int n_in,
                              void* d_out, int out_size, void* d_ws, size_t ws_size,
                              hipStream_t stream) {
  const float* x      = (const float*)d_in[0];  // [4,4096,1024] fp32
  const float* w_qkv  = (const float*)d_in[1];  // [3072,1024]   fp32
  const float* w_proj = (const float*)d_in[2];  // [1024,1024]   fp32
  const float* b_proj = (const float*)d_in[3];  // [1024]        fp32
  float* out = (float*)d_out;                   // [4,4096,1024] fp32

  char* ws = (char*)d_ws;
  // Layout (xb region reused for O after K1):
  bf16*  QKV       = (bf16*)ws;                               // 96 MiB
  float* ctx_part  = (float*)(ws + 100663296);                // 8 MiB
  float* ksum_part = (float*)(ws + 100663296 + 8388608);      // 128 KiB
  bf16*  xb        = (bf16*)(ws + 109182976);                 // 32 MiB (K1 input)
  bf16*  O         = xb;                                      // reuse after K1
  bf16*  wqkvb     = (bf16*)(ws + 109182976 + 33554432);      // 6 MiB
  bf16*  wprojb    = (bf16*)(ws + 109182976 + 33554432 + 6291456);  // 2 MiB

  // K0: fused fp32 -> bf16 conversions
  cvt3<<<2048, 256, 0, stream>>>(x, xb, w_qkv, wqkvb, w_proj, wprojb);
  // K1: QKV^T[c,m] = sum_k w_qkv[c,k]*x[m,k]; relu rows c<2048. M=3072, N=16384.
  gemm_bt64<16384, bf16><<<dim3(128, 24), 256, 0, stream>>>(wqkvb, xb, QKV, nullptr, 2048);
  // K2: partial ctx + ksum
  ctx_kernel<<<dim3(64, 8), 256, 0, stream>>>(QKV, ctx_part, ksum_part);
  // K3: O[m, c]  (overwrites xb region — xb dead after K1)
  out_kernel<<<dim3(16, 64), 256, 0, stream>>>(QKV, ctx_part, ksum_part, O);
  // K4: out[m,co] = sum_c O[m,c]*w_proj[co,c] + b_proj. M=16384, N=1024, fp32 out.
  gemm256<1024, float><<<dim3(4, 64), 512, 0, stream>>>(O, wprojb, out, b_proj, 0);
}

// Round 8
// 232.711 us; speedup vs baseline: 1.1707x; 1.0945x over previous
//
#include <hip/hip_runtime.h>
#include <hip/hip_bf16.h>

// LinearAttention on MI355X (gfx950). Inputs/outputs fp32; internal bf16 MFMA.
// B=4 N=4096 C=1024 H=16 D=64.
//  K0 cvt3:           xb/wqkvb/wprojb = bf16(x / w_qkv / w_proj)   (one kernel)
//  K1 gemm_bt<16384>: QKV^T[c,m] = sum_k w_qkv[c,k]*x[m,k], relu c<2048 rows.
//                     m97 128x128 BK=32 structure (best measured: 137.3 us).
//  K2 ctx_kernel:     per (b,h,s): partial ctx[d,e] = sum_n V[d,n]K[e,n] + ksum,
//                     LDS-staged coalesced (new), ksum via ones-MFMA.
//  K3 out_kernel:     O[m, h*64+d] = z[n] * sum_e ctx[d,e] Q[e,n]   (bf16)
//  K4 gemm256<1024>:  out[m,co] = sum_c O[m,c] w_proj[co,c] + b_proj[co] (fp32)
//                     256x256 2-phase dbuf (measured ~25 us: operands L2/L3-hot).
// Deterministic: no atomics; every ws region fully written before read.

typedef __bf16 bf16;
typedef __bf16 bf16x8 __attribute__((ext_vector_type(8)));
typedef __bf16 bf16x4 __attribute__((ext_vector_type(4)));
typedef float  f32x4  __attribute__((ext_vector_type(4)));

#define MFMA16(a, b, c) __builtin_amdgcn_mfma_f32_16x16x32_bf16((a), (b), (c), 0, 0, 0)

__device__ __forceinline__ void gload_lds16(const bf16* g, bf16* l) {
  // 16B per lane; LDS dest = wave-uniform base + lane*16 (linear layout required).
  __builtin_amdgcn_global_load_lds(
      (const __attribute__((address_space(1))) void*)g,
      (__attribute__((address_space(3))) void*)l, 16, 0, 0);
}

// ---------------------------------------------------------------------------
// K0: fused fp32 -> bf16 convert of x (4194304 f4), w_qkv (786432 f4),
//     w_proj (262144 f4). Grid-stride over the 5242880-f4 virtual concat.
// ---------------------------------------------------------------------------
__global__ __launch_bounds__(256) void cvt3(const float* __restrict__ x,  bf16* __restrict__ xb,
                                            const float* __restrict__ wq, bf16* __restrict__ wqb,
                                            const float* __restrict__ wp, bf16* __restrict__ wpb) {
  const long stride = (long)gridDim.x * 256;
  for (long i4 = (long)blockIdx.x * 256 + threadIdx.x; i4 < 5242880; i4 += stride) {
    const float* s; bf16* d; long off;
    if (i4 < 4194304)      { s = x;  d = xb;  off = i4; }
    else if (i4 < 4980736) { s = wq; d = wqb; off = i4 - 4194304; }
    else                   { s = wp; d = wpb; off = i4 - 4980736; }
    const float4 v = *(const float4*)(s + off * 4);
    bf16x4 o;
    o[0] = (bf16)v.x; o[1] = (bf16)v.y; o[2] = (bf16)v.z; o[3] = (bf16)v.w;
    *(bf16x4*)(d + off * 4) = o;
  }
}

// ---------------------------------------------------------------------------
// K1: C[i,j] = sum_k A[i,k]*B[j,k]  (m97 structure: 128x128 tile, BK=32,
// 4 waves 2x2, global_load_lds w16). Natural block order (R6: same-j blocks
// 128 apart land on the same XCD -> B-panels L2-resident; do NOT swizzle).
// ---------------------------------------------------------------------------
template <int LDC, typename CO>
__global__ __launch_bounds__(256) void gemm_bt(const bf16* __restrict__ A,
                                               const bf16* __restrict__ Bm,
                                               CO* __restrict__ Co,
                                               const float* __restrict__ bias,
                                               const int reluRows) {
  __shared__ bf16 As[128 * 32];
  __shared__ bf16 Bs[128 * 32];
  const int tid  = threadIdx.x;
  const int lane = tid & 63;
  const int w    = tid >> 6;        // wave 0..3
  const int wr   = w >> 1;          // 2x2 wave grid
  const int wc   = w & 1;
  const int i0 = blockIdx.y * 128;  // A-row block
  const int j0 = blockIdx.x * 128;  // B-row block

  // staging: per wave 2 instructions per tile, 16 rows (4 lanes/row) each
  const int srow = lane >> 2;
  const int scol = (lane & 3) * 8;
  const bf16* Ag = A  + (long)(i0 + w * 32 + srow) * 1024 + scol;
  const bf16* Bg = Bm + (long)(j0 + w * 32 + srow) * 1024 + scol;
  bf16* Asw = As + w * 32 * 32;
  bf16* Bsw = Bs + w * 32 * 32;

  const int r15  = lane & 15;
  const int koff = (lane >> 4) * 8;

  f32x4 acc[4][4] = {};

  for (int kk = 0; kk < 1024; kk += 32) {
    gload_lds16(Ag + kk,             Asw);
    gload_lds16(Ag + kk + 16 * 1024, Asw + 16 * 32);
    gload_lds16(Bg + kk,             Bsw);
    gload_lds16(Bg + kk + 16 * 1024, Bsw + 16 * 32);
    __syncthreads();  // drains vmcnt (compiler emits waitcnt before s_barrier)
    bf16x8 af[4], bfm[4];
#pragma unroll
    for (int t = 0; t < 4; ++t)
      af[t] = *(const bf16x8*)(As + (wr * 64 + t * 16 + r15) * 32 + koff);
#pragma unroll
    for (int u = 0; u < 4; ++u)
      bfm[u] = *(const bf16x8*)(Bs + (wc * 64 + u * 16 + r15) * 32 + koff);
#pragma unroll
    for (int t = 0; t < 4; ++t)
#pragma unroll
      for (int u = 0; u < 4; ++u)
        acc[t][u] = MFMA16(af[t], bfm[u], acc[t][u]);
    __syncthreads();
  }

  // D layout per 16x16 tile: row = (lane>>4)*4 + jj, col = lane&15
  const bool doRelu = (i0 < reluRows);  // block-uniform (128 | reluRows)
  const int rbase = i0 + wr * 64;
  const int cbase = j0 + wc * 64;
#pragma unroll
  for (int t = 0; t < 4; ++t) {
    const int r0 = rbase + t * 16 + (lane >> 4) * 4;
#pragma unroll
    for (int u = 0; u < 4; ++u) {
      const int cc = cbase + u * 16 + r15;
      const float bv = bias ? bias[cc] : 0.0f;
#pragma unroll
      for (int jj = 0; jj < 4; ++jj) {
        float v = acc[t][u][jj] + bv;
        if (doRelu) v = fmaxf(v, 0.0f);
        Co[(long)(r0 + jj) * LDC + cc] = (CO)v;
      }
    }
  }
}

// ---------------------------------------------------------------------------
// K2 (new): per (b,h) n-chunk s (512 cols): partial ctx[d,e] += V[d,n]K[e,n],
// partial ksum[e] += K[e,n] (ones-MFMA). K/V staged to LDS in 128-n chunks
// with coalesced 256B row segments; XOR chunk swizzle c^(row&7) via
// pre-swizzled global source + linear LDS dest; frag reads 2-way (free).
// ---------------------------------------------------------------------------
__global__ __launch_bounds__(256) void ctx_kernel(const bf16* __restrict__ QKV,
                                                  float* __restrict__ ctx_part,
                                                  float* __restrict__ ksum_part) {
  __shared__ bf16 Kl[64 * 128];   // [e][n] swizzled, 16 KiB
  __shared__ bf16 Vl[64 * 128];   // [d][n] swizzled
  const int bh = blockIdx.x;  // 0..63
  const int s  = blockIdx.y;  // 0..7
  const int b  = bh >> 4, h = bh & 15;
  const int tid = threadIdx.x, lane = tid & 63, w = tid >> 6;
  const long ldq = 16384;
  const bf16* Kp = QKV + (long)(1024 + h * 64) * ldq + b * 4096 + s * 512;
  const bf16* Vp = QKV + (long)(2048 + h * 64) * ldq + b * 4096 + s * 512;
  const int r15 = lane & 15, g = lane >> 4;
  const int x7 = r15 & 7;

  // staging: instr j covers rows w*16+j*4 .. +3; lane -> row +g, chunk lane&15;
  // source logical chunk = (lane&15) ^ (row&7)  (inverse swizzle, rule #21)
  long soff[4]; int dofs[4];
#pragma unroll
  for (int j = 0; j < 4; ++j) {
    const int row = w * 16 + j * 4 + g;
    soff[j] = (long)row * ldq + ((lane & 15) ^ (row & 7)) * 8;
    dofs[j] = (w * 16 + j * 4) * 128;
  }
  const int vrow = (w * 16 + r15) * 128;

  bf16x8 ones;
#pragma unroll
  for (int i = 0; i < 8; ++i) ones[i] = (bf16)1.0f;

  f32x4 acc[4]   = {};   // ctx: wave w owns d rows [w*16, w*16+16), 4 e-tiles
  f32x4 accks[4] = {};   // ksum via ones-MFMA (rows identical)

  for (int cc = 0; cc < 4; ++cc) {   // 4 n-chunks of 128
#pragma unroll
    for (int j = 0; j < 4; ++j) {
      gload_lds16(Kp + soff[j] + cc * 128, Kl + dofs[j]);
      gload_lds16(Vp + soff[j] + cc * 128, Vl + dofs[j]);
    }
    __syncthreads();   // vmcnt drained before barrier (compiler)
#pragma unroll
    for (int nk = 0; nk < 4; ++nk) {
      const int ch = ((nk * 4 + g) ^ x7) * 8;
      const bf16x8 av = *(const bf16x8*)(Vl + vrow + ch);
#pragma unroll
      for (int u = 0; u < 4; ++u) {
        const bf16x8 kb = *(const bf16x8*)(Kl + (u * 16 + r15) * 128 + ch);
        acc[u]   = MFMA16(av,   kb, acc[u]);
        accks[u] = MFMA16(ones, kb, accks[u]);
      }
    }
    __syncthreads();
  }

  float* cp = ctx_part + (long)(bh * 8 + s) * 4096;
#pragma unroll
  for (int u = 0; u < 4; ++u)
#pragma unroll
    for (int jj = 0; jj < 4; ++jj) {
      const int d = w * 16 + g * 4 + jj;
      const int e = u * 16 + r15;
      cp[d * 64 + e] = acc[u][jj];
    }
  if (w == 0 && g == 0) {   // row 0 of accks = ksum[e], replicated
#pragma unroll
    for (int u = 0; u < 4; ++u)
      ksum_part[(bh * 8 + s) * 64 + u * 16 + r15] = accks[u][0];
  }
}

// ---------------------------------------------------------------------------
// K3: per (b,h), 256-col n-chunk: O[(b,n), h*64+d] = z[n]*sum_e ctx[d,e]Q[e,n]
// ---------------------------------------------------------------------------
__global__ __launch_bounds__(256) void out_kernel(const bf16* __restrict__ QKV,
                                                  const float* __restrict__ ctx_part,
                                                  const float* __restrict__ ksum_part,
                                                  bf16* __restrict__ O) {
  __shared__ bf16 ctx_lds[64 * 88];   // [d][e], stride 88 (176B, 16B-mult, ~2-way)
  __shared__ bf16 qlds[256 * 80];     // [n_local][e], stride 80 (160B, 16B-mult)
  __shared__ float ksum_lds[64];
  __shared__ float zlds[256];

  const int nc = blockIdx.x;  // 0..15
  const int bh = blockIdx.y;  // 0..63
  const int b = bh >> 4, h = bh & 15;
  const int tid = threadIdx.x, lane = tid & 63, w = tid >> 6;
  const int n0 = nc * 256;
  const long ldq = 16384;

  // 1) sum 8 ctx partials -> bf16 LDS
  const float* cp = ctx_part + (long)bh * 8 * 4096;
#pragma unroll
  for (int r = 0; r < 16; ++r) {
    const int idx = tid + r * 256;  // = d*64 + e
    float v = 0.0f;
#pragma unroll
    for (int s2 = 0; s2 < 8; ++s2) v += cp[s2 * 4096 + idx];
    ctx_lds[(idx >> 6) * 88 + (idx & 63)] = (bf16)v;
  }
  if (tid < 64) {
    float v = 0.0f;
#pragma unroll
    for (int s2 = 0; s2 < 8; ++s2) v += ksum_part[(bh * 8 + s2) * 64 + tid];
    ksum_lds[tid] = v;
  }
  // 2) stage Q tile transposed: qlds[n][e]
  {
    const bf16* Qp = QKV + (long)(h * 64) * ldq + b * 4096 + n0;
    const int e = tid >> 2, seg = tid & 3;
    const bf16* qr = Qp + (long)e * ldq + seg * 64;
#pragma unroll
    for (int i = 0; i < 64; i += 8) {
      const bf16x8 v = *(const bf16x8*)(qr + i);
#pragma unroll
      for (int jj = 0; jj < 8; ++jj) qlds[(seg * 64 + i + jj) * 80 + e] = v[jj];
    }
  }
  __syncthreads();

  // 3) z[n] = 1/(ksum . Q[:,n] + eps)
  {
    float a = 0.0f;
    const bf16* qrow = qlds + tid * 80;
#pragma unroll
    for (int d = 0; d < 64; ++d) a += (float)qrow[d] * ksum_lds[d];
    zlds[tid] = 1.0f / (a + 1.1920929e-07f);
  }
  // A-frags (ctx) once per wave: 4 d-tiles x 2 k(e)-steps
  const int r15 = lane & 15;
  const int koff = (lane >> 4) * 8;
  bf16x8 afr[4][2];
#pragma unroll
  for (int t = 0; t < 4; ++t)
#pragma unroll
    for (int s2 = 0; s2 < 2; ++s2)
      afr[t][s2] = *(const bf16x8*)(ctx_lds + (t * 16 + r15) * 88 + s2 * 32 + koff);
  __syncthreads();

  // 4) each wave: 4 n-tiles of 16
#pragma unroll
  for (int nt = 0; nt < 4; ++nt) {
    const int ntile = w * 4 + nt;
    bf16x8 bfr[2];
#pragma unroll
    for (int s2 = 0; s2 < 2; ++s2)
      bfr[s2] = *(const bf16x8*)(qlds + (ntile * 16 + r15) * 80 + s2 * 32 + koff);
    f32x4 accn[4] = {};
#pragma unroll
    for (int t = 0; t < 4; ++t) {
      accn[t] = MFMA16(afr[t][0], bfr[0], accn[t]);
      accn[t] = MFMA16(afr[t][1], bfr[1], accn[t]);
    }
    const int ncol = n0 + ntile * 16 + r15;
    const float zv = zlds[ntile * 16 + r15];
    bf16* orow = O + (long)(b * 4096 + ncol) * 1024 + h * 64;
#pragma unroll
    for (int t = 0; t < 4; ++t) {
      const int d0 = t * 16 + (lane >> 4) * 4;
      bf16x4 pk;
#pragma unroll
      for (int jj = 0; jj < 4; ++jj) pk[jj] = (bf16)(accn[t][jj] * zv);
      *(bf16x4*)(orow + d0) = pk;  // 8B store, 4 consecutive d
    }
  }
}

// ---------------------------------------------------------------------------
// K4: gemm256 (2-phase dbuf): C[i,j]=sum_k A[i,k]*B[j,k]. 256x256 tile, BK=64,
// 8 waves, counted vmcnt(8) prefetch, XOR-swizzled LDS, setprio, XCD swizzle.
// Grid dim3(N/256, M/256), 512 threads. Measured ~25us on K4's shape.
// ---------------------------------------------------------------------------
template <int LDC, typename CO>
__global__ __launch_bounds__(512, 2) void gemm256(const bf16* __restrict__ A,
                                                  const bf16* __restrict__ Bm,
                                                  CO* __restrict__ Co,
                                                  const float* __restrict__ bias,
                                                  const int reluRows) {
  __shared__ bf16 As[2][256 * 64];
  __shared__ bf16 Bs[2][256 * 64];
  const int tid  = threadIdx.x;
  const int lane = tid & 63;
  const int w    = tid >> 6;      // wave 0..7
  const int wm   = w >> 2;        // 2 M-halves
  const int wn   = w & 3;         // 4 N-quarters

  const int gx = gridDim.x, gy = gridDim.y;
  const int nwg = gx * gy;
  const int id  = blockIdx.x + gx * blockIdx.y;
  const int sid = (id & 7) * (nwg >> 3) + (id >> 3);
  int bx, by;
  if (gx < gy) { bx = sid % gx; by = sid / gx; }
  else         { by = sid % gy; bx = sid / gy; }
  const int i0 = by * 256;
  const int j0 = bx * 256;

  const int lr = lane >> 3;
  const int lc = (lane & 7) ^ lr;
  const bf16* Agl = A  + (long)(i0 + 8 * w + lr) * 1024 + lc * 8;
  const bf16* Bgl = Bm + (long)(j0 + 8 * w + lr) * 1024 + lc * 8;
  const int wofs = w * 512;

  const int r15 = lane & 15, g = lane >> 4;
  const int ck[2] = { ((0 + g) ^ (r15 & 7)) * 8, ((4 + g) ^ (r15 & 7)) * 8 };
  const int arow = (wm * 128 + r15) * 64;
  const int brow = (wn * 64 + r15) * 64;

  f32x4 acc[8][4] = {};

#pragma unroll
  for (int q = 0; q < 4; ++q) {
    gload_lds16(Agl + q * 65536, &As[0][q * 4096 + wofs]);
    gload_lds16(Bgl + q * 65536, &Bs[0][q * 4096 + wofs]);
  }

  for (int kt = 0; kt < 16; ++kt) {
    const int cur = kt & 1;
    if (kt < 15) {
      const long ko = (long)(kt + 1) * 64;
#pragma unroll
      for (int q = 0; q < 4; ++q) {
        gload_lds16(Agl + ko + q * 65536, &As[cur ^ 1][q * 4096 + wofs]);
        gload_lds16(Bgl + ko + q * 65536, &Bs[cur ^ 1][q * 4096 + wofs]);
      }
      asm volatile("s_waitcnt vmcnt(8)" ::: "memory");
    } else {
      asm volatile("s_waitcnt vmcnt(0)" ::: "memory");
    }
    __builtin_amdgcn_s_barrier();
    __builtin_amdgcn_sched_barrier(0);

    const bf16* Ab = &As[cur][arow];
    const bf16* Bb = &Bs[cur][brow];
#pragma unroll
    for (int ks = 0; ks < 2; ++ks) {
      bf16x8 af[8], bfr[4];
#pragma unroll
      for (int fm = 0; fm < 8; ++fm)
        af[fm] = *(const bf16x8*)(Ab + fm * 1024 + ck[ks]);
#pragma unroll
      for (int fn = 0; fn < 4; ++fn)
        bfr[fn] = *(const bf16x8*)(Bb + fn * 1024 + ck[ks]);
      __builtin_amdgcn_s_setprio(1);
#pragma unroll
      for (int fm = 0; fm < 8; ++fm)
#pragma unroll
        for (int fn = 0; fn < 4; ++fn)
          acc[fm][fn] = MFMA16(af[fm], bfr[fn], acc[fm][fn]);
      __builtin_amdgcn_s_setprio(0);
    }
    asm volatile("s_waitcnt lgkmcnt(0)" ::: "memory");
    __builtin_amdgcn_sched_barrier(0);
    __builtin_amdgcn_s_barrier();
  }

  const bool doRelu = (i0 < reluRows);
#pragma unroll
  for (int fm = 0; fm < 8; ++fm) {
    const int r0 = i0 + wm * 128 + fm * 16 + g * 4;
#pragma unroll
    for (int fn = 0; fn < 4; ++fn) {
      const int cc = j0 + wn * 64 + fn * 16 + r15;
      const float bv = bias ? bias[cc] : 0.0f;
#pragma unroll
      for (int jj = 0; jj < 4; ++jj) {
        float v = acc[fm][fn][jj] + bv;
        if (doRelu) v = fmaxf(v, 0.0f);
        Co[(long)(r0 + jj) * LDC + cc] = (CO)v;
      }
    }
  }
}

// ---------------------------------------------------------------------------
extern "C" void kernel_launch(void* const* d_in, const int* in_sizes, int n_in,
                              void* d_out, int out_size, void* d_ws, size_t ws_size,
                              hipStream_t stream) {
  const float* x      = (const float*)d_in[0];  // [4,4096,1024] fp32
  const float* w_qkv  = (const float*)d_in[1];  // [3072,1024]   fp32
  const float* w_proj = (const float*)d_in[2];  // [1024,1024]   fp32
  const float* b_proj = (const float*)d_in[3];  // [1024]        fp32
  float* out = (float*)d_out;                   // [4,4096,1024] fp32

  char* ws = (char*)d_ws;
  // Layout (xb region reused for O after K1):
  bf16*  QKV       = (bf16*)ws;                               // 96 MiB
  float* ctx_part  = (float*)(ws + 100663296);                // 8 MiB
  float* ksum_part = (float*)(ws + 100663296 + 8388608);      // 128 KiB
  bf16*  xb        = (bf16*)(ws + 109182976);                 // 32 MiB (K1 input)
  bf16*  O         = xb;                                      // reuse after K1
  bf16*  wqkvb     = (bf16*)(ws + 109182976 + 33554432);      // 6 MiB
  bf16*  wprojb    = (bf16*)(ws + 109182976 + 33554432 + 6291456);  // 2 MiB

  // K0: fused fp32 -> bf16 conversions
  cvt3<<<2048, 256, 0, stream>>>(x, xb, w_qkv, wqkvb, w_proj, wprojb);
  // K1: QKV^T[c,m] = sum_k w_qkv[c,k]*x[m,k]; relu rows c<2048. M=3072, N=16384.
  gemm_bt<16384, bf16><<<dim3(128, 24), 256, 0, stream>>>(wqkvb, xb, QKV, nullptr, 2048);
  // K2: partial ctx + ksum (LDS-staged coalesced)
  ctx_kernel<<<dim3(64, 8), 256, 0, stream>>>(QKV, ctx_part, ksum_part);
  // K3: O[m, c]  (overwrites xb region — xb dead after K1)
  out_kernel<<<dim3(16, 64), 256, 0, stream>>>(QKV, ctx_part, ksum_part, O);
  // K4: out[m,co] = sum_c O[m,c]*w_proj[co,c] + b_proj. M=16384, N=1024, fp32 out.
  gemm256<1024, float><<<dim3(4, 64), 512, 0, stream>>>(O, wprojb, out, b_proj, 0);
}

// Round 9
// 223.580 us; speedup vs baseline: 1.2185x; 1.0408x over previous
//
#include <hip/hip_runtime.h>
#include <hip/hip_bf16.h>

// LinearAttention on MI355X (gfx950). Inputs/outputs fp32; internal bf16 MFMA.
// B=4 N=4096 C=1024 H=16 D=64.
//  K0 cvt3:           xb/wqkvb/wprojb = bf16(x / w_qkv / w_proj)   (one kernel)
//  K1 gemm_bt<16384>: QKV^T[c,m] = sum_k w_qkv[c,k]*x[m,k], relu c<2048 rows.
//                     m97 128x128 BK=32 structure (banked best: 137.3 us).
//  K2 ctx_kernel:     per (b,h,s): partial ctx[d,e] = sum_n V[d,n]K[e,n] + ksum,
//                     LDS-staged coalesced, ksum via ones-MFMA.
//  K3 out_kernel:     O[m, h*64+d] = z[n] * sum_e ctx[d,e] Q[e,n]   (bf16)
//                     grid = (bh, nc): same-bh blocks 64 apart -> same XCD ->
//                     ctx_part slab L2-resident (R6 affinity lesson).
//  K4 gemm256<1024>:  out[m,co] = sum_c O[m,c] w_proj[co,c] + b_proj[co] (fp32)
//                     256x256 2-phase dbuf (~25 us; operands L2/L3-hot).
// Deterministic: no atomics; every ws region fully written before read.

typedef __bf16 bf16;
typedef __bf16 bf16x8 __attribute__((ext_vector_type(8)));
typedef __bf16 bf16x4 __attribute__((ext_vector_type(4)));
typedef float  f32x4  __attribute__((ext_vector_type(4)));

#define MFMA16(a, b, c) __builtin_amdgcn_mfma_f32_16x16x32_bf16((a), (b), (c), 0, 0, 0)

__device__ __forceinline__ void gload_lds16(const bf16* g, bf16* l) {
  // 16B per lane; LDS dest = wave-uniform base + lane*16 (linear layout required).
  __builtin_amdgcn_global_load_lds(
      (const __attribute__((address_space(1))) void*)g,
      (__attribute__((address_space(3))) void*)l, 16, 0, 0);
}

// ---------------------------------------------------------------------------
// K0: fused fp32 -> bf16 convert of x (4194304 f4), w_qkv (786432 f4),
//     w_proj (262144 f4). Grid-stride over the 5242880-f4 virtual concat.
// ---------------------------------------------------------------------------
__global__ __launch_bounds__(256) void cvt3(const float* __restrict__ x,  bf16* __restrict__ xb,
                                            const float* __restrict__ wq, bf16* __restrict__ wqb,
                                            const float* __restrict__ wp, bf16* __restrict__ wpb) {
  const long stride = (long)gridDim.x * 256;
  for (long i4 = (long)blockIdx.x * 256 + threadIdx.x; i4 < 5242880; i4 += stride) {
    const float* s; bf16* d; long off;
    if (i4 < 4194304)      { s = x;  d = xb;  off = i4; }
    else if (i4 < 4980736) { s = wq; d = wqb; off = i4 - 4194304; }
    else                   { s = wp; d = wpb; off = i4 - 4980736; }
    const float4 v = *(const float4*)(s + off * 4);
    bf16x4 o;
    o[0] = (bf16)v.x; o[1] = (bf16)v.y; o[2] = (bf16)v.z; o[3] = (bf16)v.w;
    *(bf16x4*)(d + off * 4) = o;
  }
}

// ---------------------------------------------------------------------------
// K1: C[i,j] = sum_k A[i,k]*B[j,k]  (m97 structure: 128x128 tile, BK=32,
// 4 waves 2x2, global_load_lds w16). Natural block order (R6: same-j blocks
// 128 apart land on the same XCD -> B-panels L2-resident; do NOT swizzle).
// ---------------------------------------------------------------------------
template <int LDC, typename CO>
__global__ __launch_bounds__(256) void gemm_bt(const bf16* __restrict__ A,
                                               const bf16* __restrict__ Bm,
                                               CO* __restrict__ Co,
                                               const float* __restrict__ bias,
                                               const int reluRows) {
  __shared__ bf16 As[128 * 32];
  __shared__ bf16 Bs[128 * 32];
  const int tid  = threadIdx.x;
  const int lane = tid & 63;
  const int w    = tid >> 6;        // wave 0..3
  const int wr   = w >> 1;          // 2x2 wave grid
  const int wc   = w & 1;
  const int i0 = blockIdx.y * 128;  // A-row block
  const int j0 = blockIdx.x * 128;  // B-row block

  // staging: per wave 2 instructions per tile, 16 rows (4 lanes/row) each
  const int srow = lane >> 2;
  const int scol = (lane & 3) * 8;
  const bf16* Ag = A  + (long)(i0 + w * 32 + srow) * 1024 + scol;
  const bf16* Bg = Bm + (long)(j0 + w * 32 + srow) * 1024 + scol;
  bf16* Asw = As + w * 32 * 32;
  bf16* Bsw = Bs + w * 32 * 32;

  const int r15  = lane & 15;
  const int koff = (lane >> 4) * 8;

  f32x4 acc[4][4] = {};

  for (int kk = 0; kk < 1024; kk += 32) {
    gload_lds16(Ag + kk,             Asw);
    gload_lds16(Ag + kk + 16 * 1024, Asw + 16 * 32);
    gload_lds16(Bg + kk,             Bsw);
    gload_lds16(Bg + kk + 16 * 1024, Bsw + 16 * 32);
    __syncthreads();  // drains vmcnt (compiler emits waitcnt before s_barrier)
    bf16x8 af[4], bfm[4];
#pragma unroll
    for (int t = 0; t < 4; ++t)
      af[t] = *(const bf16x8*)(As + (wr * 64 + t * 16 + r15) * 32 + koff);
#pragma unroll
    for (int u = 0; u < 4; ++u)
      bfm[u] = *(const bf16x8*)(Bs + (wc * 64 + u * 16 + r15) * 32 + koff);
#pragma unroll
    for (int t = 0; t < 4; ++t)
#pragma unroll
      for (int u = 0; u < 4; ++u)
        acc[t][u] = MFMA16(af[t], bfm[u], acc[t][u]);
    __syncthreads();
  }

  // D layout per 16x16 tile: row = (lane>>4)*4 + jj, col = lane&15
  const bool doRelu = (i0 < reluRows);  // block-uniform (128 | reluRows)
  const int rbase = i0 + wr * 64;
  const int cbase = j0 + wc * 64;
#pragma unroll
  for (int t = 0; t < 4; ++t) {
    const int r0 = rbase + t * 16 + (lane >> 4) * 4;
#pragma unroll
    for (int u = 0; u < 4; ++u) {
      const int cc = cbase + u * 16 + r15;
      const float bv = bias ? bias[cc] : 0.0f;
#pragma unroll
      for (int jj = 0; jj < 4; ++jj) {
        float v = acc[t][u][jj] + bv;
        if (doRelu) v = fmaxf(v, 0.0f);
        Co[(long)(r0 + jj) * LDC + cc] = (CO)v;
      }
    }
  }
}

// ---------------------------------------------------------------------------
// K2: per (b,h) n-chunk s (512 cols): partial ctx[d,e] += V[d,n]K[e,n],
// partial ksum[e] += K[e,n] (ones-MFMA). K/V staged to LDS in 128-n chunks
// with coalesced 256B row segments; XOR chunk swizzle c^(row&7) via
// pre-swizzled global source + linear LDS dest; frag reads 2-way (free).
// ---------------------------------------------------------------------------
__global__ __launch_bounds__(256) void ctx_kernel(const bf16* __restrict__ QKV,
                                                  float* __restrict__ ctx_part,
                                                  float* __restrict__ ksum_part) {
  __shared__ bf16 Kl[64 * 128];   // [e][n] swizzled, 16 KiB
  __shared__ bf16 Vl[64 * 128];   // [d][n] swizzled
  const int bh = blockIdx.x;  // 0..63
  const int s  = blockIdx.y;  // 0..7
  const int b  = bh >> 4, h = bh & 15;
  const int tid = threadIdx.x, lane = tid & 63, w = tid >> 6;
  const long ldq = 16384;
  const bf16* Kp = QKV + (long)(1024 + h * 64) * ldq + b * 4096 + s * 512;
  const bf16* Vp = QKV + (long)(2048 + h * 64) * ldq + b * 4096 + s * 512;
  const int r15 = lane & 15, g = lane >> 4;
  const int x7 = r15 & 7;

  // staging: instr j covers rows w*16+j*4 .. +3; lane -> row +g, chunk lane&15;
  // source logical chunk = (lane&15) ^ (row&7)  (inverse swizzle, rule #21)
  long soff[4]; int dofs[4];
#pragma unroll
  for (int j = 0; j < 4; ++j) {
    const int row = w * 16 + j * 4 + g;
    soff[j] = (long)row * ldq + ((lane & 15) ^ (row & 7)) * 8;
    dofs[j] = (w * 16 + j * 4) * 128;
  }
  const int vrow = (w * 16 + r15) * 128;

  bf16x8 ones;
#pragma unroll
  for (int i = 0; i < 8; ++i) ones[i] = (bf16)1.0f;

  f32x4 acc[4]   = {};   // ctx: wave w owns d rows [w*16, w*16+16), 4 e-tiles
  f32x4 accks[4] = {};   // ksum via ones-MFMA (rows identical)

  for (int cc = 0; cc < 4; ++cc) {   // 4 n-chunks of 128
#pragma unroll
    for (int j = 0; j < 4; ++j) {
      gload_lds16(Kp + soff[j] + cc * 128, Kl + dofs[j]);
      gload_lds16(Vp + soff[j] + cc * 128, Vl + dofs[j]);
    }
    __syncthreads();   // vmcnt drained before barrier (compiler)
#pragma unroll
    for (int nk = 0; nk < 4; ++nk) {
      const int ch = ((nk * 4 + g) ^ x7) * 8;
      const bf16x8 av = *(const bf16x8*)(Vl + vrow + ch);
#pragma unroll
      for (int u = 0; u < 4; ++u) {
        const bf16x8 kb = *(const bf16x8*)(Kl + (u * 16 + r15) * 128 + ch);
        acc[u]   = MFMA16(av,   kb, acc[u]);
        accks[u] = MFMA16(ones, kb, accks[u]);
      }
    }
    __syncthreads();
  }

  float* cp = ctx_part + (long)(bh * 8 + s) * 4096;
#pragma unroll
  for (int u = 0; u < 4; ++u)
#pragma unroll
    for (int jj = 0; jj < 4; ++jj) {
      const int d = w * 16 + g * 4 + jj;
      const int e = u * 16 + r15;
      cp[d * 64 + e] = acc[u][jj];
    }
  if (w == 0 && g == 0) {   // row 0 of accks = ksum[e], replicated
#pragma unroll
    for (int u = 0; u < 4; ++u)
      ksum_part[(bh * 8 + s) * 64 + u * 16 + r15] = accks[u][0];
  }
}

// ---------------------------------------------------------------------------
// K3: per (b,h), 256-col n-chunk: O[(b,n), h*64+d] = z[n]*sum_e ctx[d,e]Q[e,n]
// Grid (bh, nc): same-bh blocks 64 apart (64%8==0) -> one XCD -> ctx_part
// slab (128 KB) L2-resident across its 16 readers.
// ---------------------------------------------------------------------------
__global__ __launch_bounds__(256) void out_kernel(const bf16* __restrict__ QKV,
                                                  const float* __restrict__ ctx_part,
                                                  const float* __restrict__ ksum_part,
                                                  bf16* __restrict__ O) {
  __shared__ bf16 ctx_lds[64 * 88];   // [d][e], stride 88 (176B, 16B-mult, ~2-way)
  __shared__ bf16 qlds[256 * 80];     // [n_local][e], stride 80 (160B, 16B-mult)
  __shared__ float ksum_lds[64];
  __shared__ float zlds[256];

  const int bh = blockIdx.x;  // 0..63
  const int nc = blockIdx.y;  // 0..15
  const int b = bh >> 4, h = bh & 15;
  const int tid = threadIdx.x, lane = tid & 63, w = tid >> 6;
  const int n0 = nc * 256;
  const long ldq = 16384;

  // 1) sum 8 ctx partials -> bf16 LDS
  const float* cp = ctx_part + (long)bh * 8 * 4096;
#pragma unroll
  for (int r = 0; r < 16; ++r) {
    const int idx = tid + r * 256;  // = d*64 + e
    float v = 0.0f;
#pragma unroll
    for (int s2 = 0; s2 < 8; ++s2) v += cp[s2 * 4096 + idx];
    ctx_lds[(idx >> 6) * 88 + (idx & 63)] = (bf16)v;
  }
  if (tid < 64) {
    float v = 0.0f;
#pragma unroll
    for (int s2 = 0; s2 < 8; ++s2) v += ksum_part[(bh * 8 + s2) * 64 + tid];
    ksum_lds[tid] = v;
  }
  // 2) stage Q tile transposed: qlds[n][e]
  {
    const bf16* Qp = QKV + (long)(h * 64) * ldq + b * 4096 + n0;
    const int e = tid >> 2, seg = tid & 3;
    const bf16* qr = Qp + (long)e * ldq + seg * 64;
#pragma unroll
    for (int i = 0; i < 64; i += 8) {
      const bf16x8 v = *(const bf16x8*)(qr + i);
#pragma unroll
      for (int jj = 0; jj < 8; ++jj) qlds[(seg * 64 + i + jj) * 80 + e] = v[jj];
    }
  }
  __syncthreads();

  // 3) z[n] = 1/(ksum . Q[:,n] + eps)
  {
    float a = 0.0f;
    const bf16* qrow = qlds + tid * 80;
#pragma unroll
    for (int d = 0; d < 64; ++d) a += (float)qrow[d] * ksum_lds[d];
    zlds[tid] = 1.0f / (a + 1.1920929e-07f);
  }
  // A-frags (ctx) once per wave: 4 d-tiles x 2 k(e)-steps
  const int r15 = lane & 15;
  const int koff = (lane >> 4) * 8;
  bf16x8 afr[4][2];
#pragma unroll
  for (int t = 0; t < 4; ++t)
#pragma unroll
    for (int s2 = 0; s2 < 2; ++s2)
      afr[t][s2] = *(const bf16x8*)(ctx_lds + (t * 16 + r15) * 88 + s2 * 32 + koff);
  __syncthreads();

  // 4) each wave: 4 n-tiles of 16
#pragma unroll
  for (int nt = 0; nt < 4; ++nt) {
    const int ntile = w * 4 + nt;
    bf16x8 bfr[2];
#pragma unroll
    for (int s2 = 0; s2 < 2; ++s2)
      bfr[s2] = *(const bf16x8*)(qlds + (ntile * 16 + r15) * 80 + s2 * 32 + koff);
    f32x4 accn[4] = {};
#pragma unroll
    for (int t = 0; t < 4; ++t) {
      accn[t] = MFMA16(afr[t][0], bfr[0], accn[t]);
      accn[t] = MFMA16(afr[t][1], bfr[1], accn[t]);
    }
    const int ncol = n0 + ntile * 16 + r15;
    const float zv = zlds[ntile * 16 + r15];
    bf16* orow = O + (long)(b * 4096 + ncol) * 1024 + h * 64;
#pragma unroll
    for (int t = 0; t < 4; ++t) {
      const int d0 = t * 16 + (lane >> 4) * 4;
      bf16x4 pk;
#pragma unroll
      for (int jj = 0; jj < 4; ++jj) pk[jj] = (bf16)(accn[t][jj] * zv);
      *(bf16x4*)(orow + d0) = pk;  // 8B store, 4 consecutive d
    }
  }
}

// ---------------------------------------------------------------------------
// K4: gemm256 (2-phase dbuf): C[i,j]=sum_k A[i,k]*B[j,k]. 256x256 tile, BK=64,
// 8 waves, counted vmcnt(8) prefetch, XOR-swizzled LDS, setprio, XCD swizzle.
// Grid dim3(N/256, M/256), 512 threads. Measured ~25us on K4's shape.
// ---------------------------------------------------------------------------
template <int LDC, typename CO>
__global__ __launch_bounds__(512, 2) void gemm256(const bf16* __restrict__ A,
                                                  const bf16* __restrict__ Bm,
                                                  CO* __restrict__ Co,
                                                  const float* __restrict__ bias,
                                                  const int reluRows) {
  __shared__ bf16 As[2][256 * 64];
  __shared__ bf16 Bs[2][256 * 64];
  const int tid  = threadIdx.x;
  const int lane = tid & 63;
  const int w    = tid >> 6;      // wave 0..7
  const int wm   = w >> 2;        // 2 M-halves
  const int wn   = w & 3;         // 4 N-quarters

  const int gx = gridDim.x, gy = gridDim.y;
  const int nwg = gx * gy;
  const int id  = blockIdx.x + gx * blockIdx.y;
  const int sid = (id & 7) * (nwg >> 3) + (id >> 3);
  int bx, by;
  if (gx < gy) { bx = sid % gx; by = sid / gx; }
  else         { by = sid % gy; bx = sid / gy; }
  const int i0 = by * 256;
  const int j0 = bx * 256;

  const int lr = lane >> 3;
  const int lc = (lane & 7) ^ lr;
  const bf16* Agl = A  + (long)(i0 + 8 * w + lr) * 1024 + lc * 8;
  const bf16* Bgl = Bm + (long)(j0 + 8 * w + lr) * 1024 + lc * 8;
  const int wofs = w * 512;

  const int r15 = lane & 15, g = lane >> 4;
  const int ck[2] = { ((0 + g) ^ (r15 & 7)) * 8, ((4 + g) ^ (r15 & 7)) * 8 };
  const int arow = (wm * 128 + r15) * 64;
  const int brow = (wn * 64 + r15) * 64;

  f32x4 acc[8][4] = {};

#pragma unroll
  for (int q = 0; q < 4; ++q) {
    gload_lds16(Agl + q * 65536, &As[0][q * 4096 + wofs]);
    gload_lds16(Bgl + q * 65536, &Bs[0][q * 4096 + wofs]);
  }

  for (int kt = 0; kt < 16; ++kt) {
    const int cur = kt & 1;
    if (kt < 15) {
      const long ko = (long)(kt + 1) * 64;
#pragma unroll
      for (int q = 0; q < 4; ++q) {
        gload_lds16(Agl + ko + q * 65536, &As[cur ^ 1][q * 4096 + wofs]);
        gload_lds16(Bgl + ko + q * 65536, &Bs[cur ^ 1][q * 4096 + wofs]);
      }
      asm volatile("s_waitcnt vmcnt(8)" ::: "memory");
    } else {
      asm volatile("s_waitcnt vmcnt(0)" ::: "memory");
    }
    __builtin_amdgcn_s_barrier();
    __builtin_amdgcn_sched_barrier(0);

    const bf16* Ab = &As[cur][arow];
    const bf16* Bb = &Bs[cur][brow];
#pragma unroll
    for (int ks = 0; ks < 2; ++ks) {
      bf16x8 af[8], bfr[4];
#pragma unroll
      for (int fm = 0; fm < 8; ++fm)
        af[fm] = *(const bf16x8*)(Ab + fm * 1024 + ck[ks]);
#pragma unroll
      for (int fn = 0; fn < 4; ++fn)
        bfr[fn] = *(const bf16x8*)(Bb + fn * 1024 + ck[ks]);
      __builtin_amdgcn_s_setprio(1);
#pragma unroll
      for (int fm = 0; fm < 8; ++fm)
#pragma unroll
        for (int fn = 0; fn < 4; ++fn)
          acc[fm][fn] = MFMA16(af[fm], bfr[fn], acc[fm][fn]);
      __builtin_amdgcn_s_setprio(0);
    }
    asm volatile("s_waitcnt lgkmcnt(0)" ::: "memory");
    __builtin_amdgcn_sched_barrier(0);
    __builtin_amdgcn_s_barrier();
  }

  const bool doRelu = (i0 < reluRows);
#pragma unroll
  for (int fm = 0; fm < 8; ++fm) {
    const int r0 = i0 + wm * 128 + fm * 16 + g * 4;
#pragma unroll
    for (int fn = 0; fn < 4; ++fn) {
      const int cc = j0 + wn * 64 + fn * 16 + r15;
      const float bv = bias ? bias[cc] : 0.0f;
#pragma unroll
      for (int jj = 0; jj < 4; ++jj) {
        float v = acc[fm][fn][jj] + bv;
        if (doRelu) v = fmaxf(v, 0.0f);
        Co[(long)(r0 + jj) * LDC + cc] = (CO)v;
      }
    }
  }
}

// ---------------------------------------------------------------------------
extern "C" void kernel_launch(void* const* d_in, const int* in_sizes, int n_in,
                              void* d_out, int out_size, void* d_ws, size_t ws_size,
                              hipStream_t stream) {
  const float* x      = (const float*)d_in[0];  // [4,4096,1024] fp32
  const float* w_qkv  = (const float*)d_in[1];  // [3072,1024]   fp32
  const float* w_proj = (const float*)d_in[2];  // [1024,1024]   fp32
  const float* b_proj = (const float*)d_in[3];  // [1024]        fp32
  float* out = (float*)d_out;                   // [4,4096,1024] fp32

  char* ws = (char*)d_ws;
  // Layout (xb region reused for O after K1):
  bf16*  QKV       = (bf16*)ws;                               // 96 MiB
  float* ctx_part  = (float*)(ws + 100663296);                // 8 MiB
  float* ksum_part = (float*)(ws + 100663296 + 8388608);      // 128 KiB
  bf16*  xb        = (bf16*)(ws + 109182976);                 // 32 MiB (K1 input)
  bf16*  O         = xb;                                      // reuse after K1
  bf16*  wqkvb     = (bf16*)(ws + 109182976 + 33554432);      // 6 MiB
  bf16*  wprojb    = (bf16*)(ws + 109182976 + 33554432 + 6291456);  // 2 MiB

  // K0: fused fp32 -> bf16 conversions
  cvt3<<<2048, 256, 0, stream>>>(x, xb, w_qkv, wqkvb, w_proj, wprojb);
  // K1: QKV^T[c,m] = sum_k w_qkv[c,k]*x[m,k]; relu rows c<2048. M=3072, N=16384.
  gemm_bt<16384, bf16><<<dim3(128, 24), 256, 0, stream>>>(wqkvb, xb, QKV, nullptr, 2048);
  // K2: partial ctx + ksum (LDS-staged coalesced)
  ctx_kernel<<<dim3(64, 8), 256, 0, stream>>>(QKV, ctx_part, ksum_part);
  // K3: O[m, c]  (overwrites xb region — xb dead after K1); grid (bh, nc)
  out_kernel<<<dim3(64, 16), 256, 0, stream>>>(QKV, ctx_part, ksum_part, O);
  // K4: out[m,co] = sum_c O[m,c]*w_proj[co,c] + b_proj. M=16384, N=1024, fp32 out.
  gemm256<1024, float><<<dim3(4, 64), 512, 0, stream>>>(O, wprojb, out, b_proj, 0);
}